// Round 8
// baseline (549.321 us; speedup 1.0000x reference)
//
#include <hip/hip_runtime.h>
#include <hip/hip_bf16.h>
#include <stdint.h>

typedef __bf16 bf16;
typedef __bf16 bf16x8 __attribute__((ext_vector_type(8)));
typedef __bf16 bf16x4 __attribute__((ext_vector_type(4)));
typedef float f32x4 __attribute__((ext_vector_type(4)));
typedef float f32x16 __attribute__((ext_vector_type(16)));
typedef uint32_t u32x2 __attribute__((ext_vector_type(2)));
typedef uint32_t u32x4 __attribute__((ext_vector_type(4)));

#define E_DIM 2048
#define HEADS 16
#define HD 128
#define SEQ 2048
#define BATCH 2
#define NTOK 4096
#define NSLOT 8

// 1/sqrt(128) * log2(e): folded into Q / TQ at projection time
#define QSCALE (0.08838834764831845f * 1.4426950408889634f)

#define WAITV(N) asm volatile("s_waitcnt vmcnt(" #N ")" ::: "memory")

__device__ __forceinline__ void gload_lds16(const void* g, void* lds) {
  __builtin_amdgcn_global_load_lds(
      (const __attribute__((address_space(1))) uint32_t*)g,
      (__attribute__((address_space(3))) uint32_t*)lds, 16, 0, 0);
}

// ---------------- f32 -> bf16 convert, 8 elems/thread, grid-stride ----------------
__global__ __launch_bounds__(256) void cvt_f32_bf16_kernel(
    const float* __restrict__ src, bf16* __restrict__ dst, int n8)
{
  for (int i = blockIdx.x * 256 + threadIdx.x; i < n8; i += gridDim.x * 256) {
    const f32x4 a = *(const f32x4*)(src + i * 8);
    const f32x4 b = *(const f32x4*)(src + i * 8 + 4);
    bf16x8 o;
#pragma unroll
    for (int j = 0; j < 4; j++) { o[j] = (bf16)a[j]; o[4 + j] = (bf16)b[j]; }
    *(bf16x8*)(dst + i * 8) = o;
  }
}

struct ProjArgs {
  const bf16* W[4];
  const float* bias[4];
  void* out[4];
  int mode[4];     // 0: f32 row-major [M][N=2048]; 1: bf16 [B,H,S,D]; 2: bf16 [B,H,D,S]
  float scale[4];  // applied AFTER bias
};

// ---------------- 256x256 NT GEMM, BK=64 as 2 k-slices, counted-vmcnt pipeline ------
// LDS: [2 dbuf][2 kslice] x (A 256x32 + B 256x32) bf16 = 128 KiB.
// Rows are 64B = 4 x 16B slots, phys slot = logical ^ (row&3) (uniform 8-deep
// bank access on ds_read_b128 fragments = conflict-free). Staged via
// global_load_lds, 4 loads/thread per (tile,slice): A j=0/1, B j=0/1.
// Schedule per tile t (dbuf d=t&1):
//   ph0: issue slice1(t+1) | ds_read kk0 | 32 MFMA | vmcnt(8) | s_barrier
//   ph1: issue slice0(t+2) | ds_read kk1 | 32 MFMA | vmcnt(8) | s_barrier
// Invariant at tile entry: slice0(t) landed; outstanding = {slice1(t), slice0(t+1)}.
// Loads never drain below 8 in flight; each gets ~1.5 tiles of MFMA cover (T3+T4).
__global__ __launch_bounds__(512, 2) void gemm256_kernel(
    const bf16* __restrict__ A, ProjArgs pa, int nbm, int nbn)
{
  __shared__ char LdsA[2 * 2 * 16384];
  __shared__ char LdsB[2 * 2 * 16384];

  const int nwg = gridDim.x;
  const int qch = nwg >> 3;
  const int wg = (blockIdx.x & 7) * qch + (blockIdx.x >> 3);
  const int bm = wg % nbm;
  const int rest = wg / nbm;
  const int bn = rest % nbn;
  const int z = rest / nbn;

  const bf16* __restrict__ W = pa.W[z];
  const float* __restrict__ bias = pa.bias[z];
  void* __restrict__ out = pa.out[z];
  const int mode = pa.mode[z];
  const float scale = pa.scale[z];

  const int tid = threadIdx.x;
  const int lane = tid & 63;
  const int w = tid >> 6;          // 0..7
  const int wr = w >> 2;           // 0..1 (M)
  const int wc = w & 3;            // 0..3 (N)
  const int g = lane >> 4, c = lane & 15;

  // staging source map: thread -> (row = tid>>2 within 128-row group, phys slot tid&3)
  const int rw = tid >> 2;                              // 0..127
  const int sc = ((tid & 3) ^ (rw & 3)) * 8;            // inverse-swizzled source col
  const bf16* Asrc = A + (size_t)(bm * 256 + rw) * 2048 + sc;
  const bf16* Bsrc = W + (size_t)(bn * 256 + rw) * 2048 + sc;

  // stage slice s (32 cols) of K-tile T into dbuf T&1: 4 gload_lds/thread
  auto stage = [&](int T, int s) {
    const int q4 = ((T & 1) * 2 + s) * 16384;
    const int k0 = T * 64 + s * 32;
#pragma unroll
    for (int j = 0; j < 2; j++) {
      gload_lds16(Asrc + (size_t)(j * 128) * 2048 + k0, LdsA + q4 + j * 8192 + tid * 16);
      gload_lds16(Bsrc + (size_t)(j * 128) * 2048 + k0, LdsB + q4 + j * 8192 + tid * 16);
    }
  };

  f32x4 acc[8][4] = {};

  // prologue: slice0(0), slice1(0), slice0(1); wait slice0(0) landed (12 -> 8)
  stage(0, 0); stage(0, 1); stage(1, 0);
  WAITV(8);
  __builtin_amdgcn_s_barrier();

  const int NT = 2048 / 64;   // 32
  for (int t = 0; t < NT; t++) {
    const int d = t & 1;
#pragma unroll
    for (int ph = 0; ph < 2; ph++) {
      // issue next staging first
      if (ph == 0) { if (t + 1 < NT) stage(t + 1, 1); }
      else         { if (t + 2 < NT) stage(t + 2, 0); }

      // fragment reads from [d][slice=ph]
      const char* Aq = LdsA + (d * 2 + ph) * 16384;
      const char* Bq = LdsB + (d * 2 + ph) * 16384;
      bf16x8 af[8], bfr[4];
#pragma unroll
      for (int n = 0; n < 4; n++) {
        const int row = wc * 64 + n * 16 + c;
        bfr[n] = *(const bf16x8*)(Bq + row * 64 + ((g ^ (row & 3)) * 16));
      }
#pragma unroll
      for (int mi = 0; mi < 8; mi++) {
        const int row = wr * 128 + mi * 16 + c;
        af[mi] = *(const bf16x8*)(Aq + row * 64 + ((g ^ (row & 3)) * 16));
      }
      __builtin_amdgcn_s_setprio(1);
#pragma unroll
      for (int mi = 0; mi < 8; mi++)
#pragma unroll
        for (int n = 0; n < 4; n++)
          acc[mi][n] = __builtin_amdgcn_mfma_f32_16x16x32_bf16(af[mi], bfr[n], acc[mi][n], 0, 0, 0);
      __builtin_amdgcn_s_setprio(0);

      // counted wait + barrier (never drain to 0 in steady state)
      if (ph == 0) {
        if (t == NT - 1) { WAITV(0); } else { WAITV(8); }
        __builtin_amdgcn_s_barrier();
      } else {
        if (t < NT - 2)       { WAITV(8); __builtin_amdgcn_s_barrier(); }
        else if (t == NT - 2) { WAITV(4); __builtin_amdgcn_s_barrier(); }
        // t == NT-1: loop ends
      }
    }
  }

  // epilogue: D[r][c]: col = lane&15, row = (lane>>4)*4 + j  (per 16x16 frag)
#pragma unroll
  for (int mi = 0; mi < 8; mi++) {
#pragma unroll
    for (int n = 0; n < 4; n++) {
      const int col = bn * 256 + wc * 64 + n * 16 + c;
      const float bv = bias[col];
#pragma unroll
      for (int j = 0; j < 4; j++) {
        const int row = bm * 256 + wr * 128 + mi * 16 + g * 4 + j;
        const float v = (acc[mi][n][j] + bv) * scale;
        if (mode == 0) {
          ((float*)out)[(size_t)row * E_DIM + col] = v;
        } else {
          const int b = row >> 11, s = row & 2047;
          const int h = col >> 7, d2 = col & 127;
          size_t idx;
          if (mode == 1) idx = (((size_t)(b * HEADS + h)) * SEQ + s) * HD + d2;
          else           idx = (((size_t)(b * HEADS + h)) * HD + d2) * SEQ + s;
          ((bf16*)out)[idx] = (bf16)v;
        }
      }
    }
  }
}

// ---------------- 128x128 NT GEMM (round-3 version) for the final projection ----------
__global__ __launch_bounds__(256) void gemm_nt_kernel(
    const bf16* __restrict__ A, ProjArgs pa, int M, int N, int K)
{
  __shared__ bf16 As[2][128 * 32];
  __shared__ bf16 Bs[2][128 * 32];

  const int z = blockIdx.z;
  const bf16* __restrict__ W = pa.W[z];
  const float* __restrict__ bias = pa.bias[z];
  void* __restrict__ out = pa.out[z];
  const int mode = pa.mode[z];
  const float scale = pa.scale[z];

  const int tid = threadIdx.x;
  const int lane = tid & 63;
  const int w = tid >> 6;
  const int wr = w >> 1, wc = w & 1;
  const int g = lane >> 4, c = lane & 15;
  const int bm = blockIdx.x, bn = blockIdx.y;

  f32x4 acc[4][4] = {};

  const int srow = lane >> 2;          // 0..15
  const int scol = (lane & 3) * 8;     // 0,8,16,24
  const bf16* Ab = A + (size_t)(bm * 128 + srow) * K + scol;
  const bf16* Wb = W + (size_t)(bn * 128 + srow) * K + scol;

  auto stage = [&](int k0, int buf) {
#pragma unroll
    for (int i = 0; i < 2; ++i) {
      const int chunk = w * 2 + i;     // 0..7, each 1024B = 16 rows x 32 cols
      gload_lds16(Ab + (size_t)(chunk * 16) * K + k0, (char*)(&As[buf][0]) + chunk * 1024);
      gload_lds16(Wb + (size_t)(chunk * 16) * K + k0, (char*)(&Bs[buf][0]) + chunk * 1024);
    }
  };

  stage(0, 0);
  __syncthreads();
  int cur = 0;

  for (int k0 = 0; k0 < K; k0 += 32) {
    if (k0 + 32 < K) stage(k0 + 32, cur ^ 1);
    bf16x8 af[4], bfr[4];
#pragma unroll
    for (int m = 0; m < 4; m++)
      af[m] = *(const bf16x8*)(&As[cur][0] + (wr * 64 + m * 16 + c) * 32 + g * 8);
#pragma unroll
    for (int n = 0; n < 4; n++)
      bfr[n] = *(const bf16x8*)(&Bs[cur][0] + (wc * 64 + n * 16 + c) * 32 + g * 8);
#pragma unroll
    for (int m = 0; m < 4; m++)
#pragma unroll
      for (int n = 0; n < 4; n++)
        acc[m][n] = __builtin_amdgcn_mfma_f32_16x16x32_bf16(af[m], bfr[n], acc[m][n], 0, 0, 0);
    __syncthreads();
    cur ^= 1;
  }

#pragma unroll
  for (int m = 0; m < 4; m++) {
#pragma unroll
    for (int n = 0; n < 4; n++) {
      const int col = bn * 128 + wc * 64 + n * 16 + c;
      const float bv = bias[col];
#pragma unroll
      for (int j = 0; j < 4; j++) {
        const int row = bm * 128 + wr * 64 + m * 16 + g * 4 + j;
        const float v = (acc[m][n][j] + bv) * scale;
        if (mode == 0) {
          ((float*)out)[(size_t)row * N + col] = v;
        } else {
          const int b = row >> 11, s = row & 2047;
          const int h = col >> 7, d = col & 127;
          size_t idx;
          if (mode == 1) idx = (((size_t)(b * HEADS + h)) * SEQ + s) * HD + d;
          else           idx = (((size_t)(b * HEADS + h)) * HD + d) * SEQ + s;
          ((bf16*)out)[idx] = (bf16)v;
        }
      }
    }
  }
}

// ---------------- slots projections: tk/tv = slots @ W^T + b, f32 [8][2048] ----------------
__global__ __launch_bounds__(256) void slots_proj_kernel(
    const float* __restrict__ slots,
    const float* __restrict__ Wk, const float* __restrict__ bk,
    const float* __restrict__ Wv, const float* __restrict__ bv,
    float* __restrict__ tk, float* __restrict__ tv)
{
  const int col = blockIdx.x * 256 + threadIdx.x;
  const int slot = blockIdx.y;
  const int mat = blockIdx.z;
  const float* W = mat ? Wv : Wk;
  const float* bias = mat ? bv : bk;
  float* out = mat ? tv : tk;
  const float* xr = slots + (size_t)slot * E_DIM;
  const float* wr = W + (size_t)col * E_DIM;
  float acc = 0.f;
  for (int k = 0; k < E_DIM; k += 4) {
    const f32x4 a = *(const f32x4*)(xr + k);
    const f32x4 b4 = *(const f32x4*)(wr + k);
#pragma unroll
    for (int i = 0; i < 4; i++) acc += a[i] * b4[i];
  }
  out[(size_t)slot * E_DIM + col] = acc + bias[col];
}

// ---------------- flash attention: 4-wave 32x32 MFMA, 2 blocks/CU ----------------
// Q pre-scaled by QSCALE. Q,K: bf16 [B,H,S,D]; Vt: bf16 [B,H,D,S]; out: bf16 [B,S,E].
// 256 threads = 4 waves; each wave owns 32 q rows (block = 128 q). KV tile 64,
// double-buffered global_load_lds staging, single barrier per tile. 64 KiB LDS
// -> 2 blocks/CU so cross-block overlap hides the per-tile barrier drain (m114).
__global__ __launch_bounds__(256) void flash_attn_kernel(
    const bf16* __restrict__ Qg, const bf16* __restrict__ Kg,
    const bf16* __restrict__ Vtg, bf16* __restrict__ Og)
{
  __shared__ char Ks[2][64 * 256];    // [kv][d] bf16, 256B rows, slot ^= r&15
  __shared__ char Vs[2][128 * 128];   // [d][kv] bf16, 128B rows, slot ^= r&7

  const int orig = blockIdx.x;                 // 512 blocks
  const int logical = (orig & 7) * 64 + (orig >> 3);   // XCD k -> bh in [4k,4k+4)
  const int qt = logical & 15;
  const int bh = logical >> 4;

  const int tid = threadIdx.x;
  const int lane = tid & 63;
  const int w = tid >> 6;          // 0..3
  const int q = lane & 31;
  const int hi = lane >> 5;
  const int b = bh >> 4, h = bh & 15;
  const int q0 = qt * 128 + w * 32;

  const bf16* Qb = Qg + ((size_t)bh * SEQ + q0) * HD;
  const bf16* Kb = Kg + (size_t)bh * SEQ * HD;
  const bf16* Vb = Vtg + (size_t)bh * HD * SEQ;

  // staging: 256 threads x (4 K-chunks + 4 V-chunks) x 16B = 16KB K + 16KB V
  auto stage = [&](int kv0, int buf) {
#pragma unroll
    for (int i = 0; i < 4; i++) {
      const int p = (tid + i * 256) * 16;
      { const int r = p >> 8; const int s16 = (p >> 4) & 15;
        gload_lds16(Kb + (size_t)(kv0 + r) * HD + (s16 ^ (r & 15)) * 8, &Ks[buf][0] + p); }
      { const int r = p >> 7; const int s8 = (p >> 4) & 7;
        gload_lds16(Vb + (size_t)r * SEQ + kv0 + (s8 ^ (r & 7)) * 8, &Vs[buf][0] + p); }
    }
  };

  // Q B-operand fragments: qf[kc][j] = Q[q][kc*16 + 8*hi + j]
  bf16x8 qf[8];
#pragma unroll
  for (int kc = 0; kc < 8; kc++)
    qf[kc] = *(const bf16x8*)(Qb + (size_t)q * HD + kc * 16 + hi * 8);

  stage(0, 0);
  __syncthreads();
  int cur = 0;

  f32x16 o[4] = {};                  // O^T[d][q], 4 d-blocks of 32
  float mrun = -1e30f, lsum = 0.f;

  for (int kv0 = 0; kv0 < SEQ; kv0 += 64) {
    if (kv0 + 64 < SEQ) stage(kv0 + 64, cur ^ 1);

    // S^T[kv][q] = K · Q^T, two 32-kv blocks
    f32x16 st[2] = {};
    __builtin_amdgcn_s_setprio(1);
#pragma unroll
    for (int kc = 0; kc < 8; kc++) {
#pragma unroll
      for (int blk = 0; blk < 2; blk++) {
        const int rt = blk * 32 + q;
        const int sl = (2 * kc + hi) ^ (rt & 15);
        const bf16x8 kf = *(const bf16x8*)(&Ks[cur][0] + rt * 256 + sl * 16);
        st[blk] = __builtin_amdgcn_mfma_f32_32x32x16_bf16(kf, qf[kc], st[blk], 0, 0, 0);
      }
    }
    __builtin_amdgcn_s_setprio(0);

    // softmax: one q per lane; 32 local kv + the 32 in lane^32
    float t[16];
#pragma unroll
    for (int i = 0; i < 16; i++) t[i] = fmaxf(st[0][i], st[1][i]);
#pragma unroll
    for (int s2 = 8; s2 > 0; s2 >>= 1)
#pragma unroll
      for (int i = 0; i < 8; i++) if (i < s2) t[i] = fmaxf(t[i], t[i + s2]);
    float lm = t[0];
    lm = fmaxf(lm, __shfl_xor(lm, 32));

    float fsc = 1.0f;
    if (__any(lm > mrun + 8.0f)) {             // defer-max (T13), wave-uniform
      const float mn = fmaxf(mrun, lm);
      fsc = exp2f(mrun - mn);
      mrun = mn;
#pragma unroll
      for (int db = 0; db < 4; db++)
#pragma unroll
        for (int i = 0; i < 16; i++) o[db][i] *= fsc;
    }

    float ps0 = 0.f, ps1 = 0.f, ps2 = 0.f, ps3 = 0.f;
#pragma unroll
    for (int blk = 0; blk < 2; blk++)
#pragma unroll
      for (int i = 0; i < 16; i += 4) {
        const float p0 = exp2f(st[blk][i]     - mrun);
        const float p1 = exp2f(st[blk][i + 1] - mrun);
        const float p2 = exp2f(st[blk][i + 2] - mrun);
        const float p3 = exp2f(st[blk][i + 3] - mrun);
        st[blk][i] = p0; st[blk][i + 1] = p1; st[blk][i + 2] = p2; st[blk][i + 3] = p3;
        ps0 += p0; ps1 += p1; ps2 += p2; ps3 += p3;
      }
    lsum = lsum * fsc + ((ps0 + ps1) + (ps2 + ps3));

    // P (C-layout) -> PV B-operand fragments via 2 shfl_xor(32) per 16-kv chunk
    bf16x8 pb[2][2];
#pragma unroll
    for (int blk = 0; blk < 2; blk++)
#pragma unroll
      for (int c2 = 0; c2 < 2; c2++) {
        bf16x4 Lv, Hv;
#pragma unroll
        for (int i = 0; i < 4; i++) {
          Lv[i] = (bf16)st[blk][8 * c2 + i];
          Hv[i] = (bf16)st[blk][8 * c2 + 4 + i];
        }
        const u32x2 Lu = __builtin_bit_cast(u32x2, Lv);
        const u32x2 Hu = __builtin_bit_cast(u32x2, Hv);
        const uint32_t s0 = hi ? Lu.x : Hu.x;     // half1 sends L, half0 sends H
        const uint32_t s1 = hi ? Lu.y : Hu.y;
        const uint32_t x0 = (uint32_t)__shfl_xor((int)s0, 32);
        const uint32_t x1 = (uint32_t)__shfl_xor((int)s1, 32);
        u32x4 bv;
        bv.x = hi ? x0 : Lu.x;
        bv.y = hi ? x1 : Lu.y;
        bv.z = hi ? Hu.x : x0;
        bv.w = hi ? Hu.y : x1;
        pb[blk][c2] = __builtin_bit_cast(bf16x8, bv);
      }

    // O^T[d][q] += V^T[d][kv] · P^T[kv][q]
    __builtin_amdgcn_s_setprio(1);
#pragma unroll
    for (int db = 0; db < 4; db++) {
      const int rt = db * 32 + q;
#pragma unroll
      for (int blk = 0; blk < 2; blk++)
#pragma unroll
        for (int c2 = 0; c2 < 2; c2++) {
          const int sl = (blk * 4 + c2 * 2 + hi) ^ (rt & 7);
          const bf16x8 vf = *(const bf16x8*)(&Vs[cur][0] + rt * 128 + sl * 16);
          o[db] = __builtin_amdgcn_mfma_f32_32x32x16_bf16(vf, pb[blk][c2], o[db], 0, 0, 0);
        }
    }
    __builtin_amdgcn_s_setprio(0);

    __syncthreads();   // drains own staging vmcnt; guards dbuf reuse
    cur ^= 1;
  }

  // epilogue: total l = own + other half; per-lane normalize; vec4 stores
  const float lt = lsum + __shfl_xor(lsum, 32);
  const float linv = 1.0f / lt;
  bf16* Orow = Og + ((size_t)b * SEQ + q0 + q) * E_DIM + h * HD;
#pragma unroll
  for (int db = 0; db < 4; db++)
#pragma unroll
    for (int g4 = 0; g4 < 4; g4++) {
      bf16x4 ov;
#pragma unroll
      for (int i = 0; i < 4; i++) ov[i] = (bf16)(o[db][g4 * 4 + i] * linv);
      *(bf16x4*)(Orow + db * 32 + g4 * 8 + hi * 4) = ov;
    }
}

// ---------------- fused thought cross-attn + LayerNorm ----------------
__global__ __launch_bounds__(256) void thought_ln_kernel(
    const bf16* __restrict__ TQ, const float* __restrict__ TK,
    const float* __restrict__ TV, const bf16* __restrict__ ATT,
    const float* __restrict__ gamma, const float* __restrict__ beta,
    bf16* __restrict__ Y)
{
  __shared__ float wsum[4], wsq[4];
  const int tid = threadIdx.x;
  const int lane = tid & 63;
  const int w = tid >> 6;
  const int tok = blockIdx.x;            // b*SEQ + s
  const int b = tok >> 11, s = tok & 2047;
  const int e0 = tid * 8;
  const int h = e0 >> 7;
  const int d0 = e0 & 127;

  const bf16x8 av = *(const bf16x8*)(ATT + (size_t)tok * E_DIM + e0);
  float v[8];
#pragma unroll
  for (int i = 0; i < 8; i++) v[i] = (float)av[i];

  const bf16x8 qv8 = *(const bf16x8*)(TQ + (((size_t)(b * HEADS + h)) * SEQ + s) * HD + d0);
  float qv[8];
#pragma unroll
  for (int i = 0; i < 8; i++) qv[i] = (float)qv8[i];

  float dts[NSLOT];
#pragma unroll
  for (int sl = 0; sl < NSLOT; sl++) {
    const float* tkr = TK + (size_t)sl * E_DIM + e0;
    const f32x4 k0 = *(const f32x4*)(tkr);
    const f32x4 k1 = *(const f32x4*)(tkr + 4);
    float dp = 0.f;
#pragma unroll
    for (int i = 0; i < 4; i++) dp += qv[i] * k0[i] + qv[4 + i] * k1[i];
    dp += __shfl_xor(dp, 1);
    dp += __shfl_xor(dp, 2);
    dp += __shfl_xor(dp, 4);
    dp += __shfl_xor(dp, 8);
    dts[sl] = dp;
  }
  float mx = dts[0];
#pragma unroll
  for (int sl = 1; sl < NSLOT; sl++) mx = fmaxf(mx, dts[sl]);
  float p[NSLOT], den = 0.f;
#pragma unroll
  for (int sl = 0; sl < NSLOT; sl++) { p[sl] = exp2f(dts[sl] - mx); den += p[sl]; }
  const float dinv = 1.0f / den;
#pragma unroll
  for (int sl = 0; sl < NSLOT; sl++) {
    const float pn = p[sl] * dinv;
    const float* tvr = TV + (size_t)sl * E_DIM + e0;
    const f32x4 v0 = *(const f32x4*)(tvr);
    const f32x4 v1 = *(const f32x4*)(tvr + 4);
#pragma unroll
    for (int i = 0; i < 4; i++) { v[i] += pn * v0[i]; v[4 + i] += pn * v1[i]; }
  }

  float sm = 0.f, sq = 0.f;
#pragma unroll
  for (int i = 0; i < 8; i++) { sm += v[i]; sq += v[i] * v[i]; }
#pragma unroll
  for (int d = 1; d < 64; d <<= 1) { sm += __shfl_xor(sm, d); sq += __shfl_xor(sq, d); }
  if (lane == 0) { wsum[w] = sm; wsq[w] = sq; }
  __syncthreads();
  const float ts = wsum[0] + wsum[1] + wsum[2] + wsum[3];
  const float tq2 = wsq[0] + wsq[1] + wsq[2] + wsq[3];
  const float mean = ts * (1.f / E_DIM);
  const float var = tq2 * (1.f / E_DIM) - mean * mean;
  const float rstd = rsqrtf(var + 1e-5f);
  const f32x4 g0 = *(const f32x4*)(gamma + e0);
  const f32x4 g1 = *(const f32x4*)(gamma + e0 + 4);
  const f32x4 b0 = *(const f32x4*)(beta + e0);
  const f32x4 b1 = *(const f32x4*)(beta + e0 + 4);
  bf16x8 outv;
#pragma unroll
  for (int i = 0; i < 4; i++) {
    outv[i]     = (bf16)((v[i]     - mean) * rstd * g0[i] + b0[i]);
    outv[4 + i] = (bf16)((v[4 + i] - mean) * rstd * g1[i] + b1[i]);
  }
  *(bf16x8*)(Y + (size_t)tok * E_DIM + e0) = outv;
}

extern "C" void kernel_launch(void* const* d_in, const int* in_sizes, int n_in,
                              void* d_out, int out_size, void* d_ws, size_t ws_size,
                              hipStream_t stream) {
  (void)in_sizes; (void)n_in; (void)out_size; (void)ws_size;
  const float* x     = (const float*)d_in[0];
  const float* slots = (const float*)d_in[1];
  const float* Wq  = (const float*)d_in[2];   const float* bq  = (const float*)d_in[3];
  const float* Wk  = (const float*)d_in[4];   const float* bk  = (const float*)d_in[5];
  const float* Wv  = (const float*)d_in[6];   const float* bv  = (const float*)d_in[7];
  const float* Wtq = (const float*)d_in[8];   const float* btq = (const float*)d_in[9];
  const float* Wtk = (const float*)d_in[10];  const float* btk = (const float*)d_in[11];
  const float* Wtv = (const float*)d_in[12];  const float* btv = (const float*)d_in[13];
  const float* Wo  = (const float*)d_in[14];  const float* bo  = (const float*)d_in[15];
  const float* gamma = (const float*)d_in[16];
  const float* beta  = (const float*)d_in[17];

  uint8_t* ws = (uint8_t*)d_ws;
  const size_t BUF  = (size_t)NTOK * E_DIM * sizeof(bf16);    // 16 MiB (activations)
  const size_t WBUF = (size_t)E_DIM * E_DIM * sizeof(bf16);   // 8 MiB (weights)
  bf16* xb   = (bf16*)(ws + 0 * BUF);          // [B,S,E] bf16 x
  bf16* qb   = (bf16*)(ws + 1 * BUF);          // [B,H,S,D] (pre-scaled)
  bf16* kb   = (bf16*)(ws + 2 * BUF);          // [B,H,S,D]
  bf16* vtb  = (bf16*)(ws + 3 * BUF);          // [B,H,D,S]
  bf16* tqb  = (bf16*)(ws + 4 * BUF);          // [B,H,S,D] (pre-scaled)
  bf16* attb = (bf16*)(ws + 5 * BUF);          // [B,S,E] flash output
  bf16* nrmb = qb;                             // alias: qb dead after flash
  uint8_t* wp = ws + 6 * BUF;
  bf16* Wqb  = (bf16*)(wp + 0 * WBUF);
  bf16* Wkb  = (bf16*)(wp + 1 * WBUF);
  bf16* Wvb  = (bf16*)(wp + 2 * WBUF);
  bf16* Wtqb = (bf16*)(wp + 3 * WBUF);
  bf16* Wob  = (bf16*)(wp + 4 * WBUF);
  float* tkb = (float*)(wp + 5 * WBUF);               // [8][E] f32
  float* tvb = (float*)(wp + 5 * WBUF + 128 * 1024);  // [8][E] f32

  // --- convert f32 -> bf16 for MFMA consumers ---
  const int WN8 = E_DIM * E_DIM / 8;   // 524288
  const int XN8 = NTOK * E_DIM / 8;    // 1048576
  cvt_f32_bf16_kernel<<<dim3(2048), 256, 0, stream>>>(x, xb, XN8);
  cvt_f32_bf16_kernel<<<dim3(1024), 256, 0, stream>>>(Wq, Wqb, WN8);
  cvt_f32_bf16_kernel<<<dim3(1024), 256, 0, stream>>>(Wk, Wkb, WN8);
  cvt_f32_bf16_kernel<<<dim3(1024), 256, 0, stream>>>(Wv, Wvb, WN8);
  cvt_f32_bf16_kernel<<<dim3(1024), 256, 0, stream>>>(Wtq, Wtqb, WN8);
  cvt_f32_bf16_kernel<<<dim3(1024), 256, 0, stream>>>(Wo, Wob, WN8);

  // --- projections (Q and TQ pre-scaled by 1/sqrt(D)*log2e) ---
  ProjArgs pa;
  pa.W[0] = Wqb;  pa.bias[0] = bq;  pa.out[0] = qb;  pa.mode[0] = 1; pa.scale[0] = QSCALE;
  pa.W[1] = Wkb;  pa.bias[1] = bk;  pa.out[1] = kb;  pa.mode[1] = 1; pa.scale[1] = 1.0f;
  pa.W[2] = Wvb;  pa.bias[2] = bv;  pa.out[2] = vtb; pa.mode[2] = 2; pa.scale[2] = 1.0f;
  pa.W[3] = Wtqb; pa.bias[3] = btq; pa.out[3] = tqb; pa.mode[3] = 1; pa.scale[3] = QSCALE;
  gemm256_kernel<<<dim3(16 * 8 * 4), 512, 0, stream>>>(xb, pa, 16, 8);

  slots_proj_kernel<<<dim3(E_DIM / 256, NSLOT, 2), 256, 0, stream>>>(
      slots, Wtk, btk, Wtv, btv, tkb, tvb);

  // --- attention streams ---
  flash_attn_kernel<<<dim3((SEQ / 128) * BATCH * HEADS), 256, 0, stream>>>(
      qb, kb, vtb, attb);
  thought_ln_kernel<<<dim3(NTOK), 256, 0, stream>>>(
      tqb, tkb, tvb, attb, gamma, beta, nrmb);

  // --- output projection (f32 out), 128^2 tiles: 512 blocks = 2/CU ---
  ProjArgs po;
  po.W[0] = Wob; po.bias[0] = bo; po.out[0] = d_out; po.mode[0] = 0; po.scale[0] = 1.0f;
  po.W[1] = po.W[2] = po.W[3] = Wob;
  po.bias[1] = po.bias[2] = po.bias[3] = bo;
  po.out[1] = po.out[2] = po.out[3] = d_out;
  po.mode[1] = po.mode[2] = po.mode[3] = 0;
  po.scale[1] = po.scale[2] = po.scale[3] = 1.0f;
  gemm_nt_kernel<<<dim3(NTOK / 128, E_DIM / 128, 1), 256, 0, stream>>>(
      nrmb, po, NTOK, E_DIM, E_DIM);
}

// Round 9
// 482.408 us; speedup vs baseline: 1.1387x; 1.1387x over previous
//
#include <hip/hip_runtime.h>
#include <hip/hip_bf16.h>
#include <stdint.h>

typedef __bf16 bf16;
typedef __bf16 bf16x8 __attribute__((ext_vector_type(8)));
typedef __bf16 bf16x4 __attribute__((ext_vector_type(4)));
typedef float f32x4 __attribute__((ext_vector_type(4)));
typedef float f32x16 __attribute__((ext_vector_type(16)));
typedef uint32_t u32x2 __attribute__((ext_vector_type(2)));
typedef uint32_t u32x4 __attribute__((ext_vector_type(4)));

#define E_DIM 2048
#define HEADS 16
#define HD 128
#define SEQ 2048
#define BATCH 2
#define NTOK 4096
#define NSLOT 8

// 1/sqrt(128) * log2(e): folded into Q / TQ at projection time
#define QSCALE (0.08838834764831845f * 1.4426950408889634f)

#define WAITV(N) asm volatile("s_waitcnt vmcnt(" #N ")" ::: "memory")

__device__ __forceinline__ void gload_lds16(const void* g, void* lds) {
  __builtin_amdgcn_global_load_lds(
      (const __attribute__((address_space(1))) uint32_t*)g,
      (__attribute__((address_space(3))) uint32_t*)lds, 16, 0, 0);
}

// ---------------- f32 -> bf16 convert, 8 elems/thread, grid-stride ----------------
__global__ __launch_bounds__(256) void cvt_f32_bf16_kernel(
    const float* __restrict__ src, bf16* __restrict__ dst, int n8)
{
  for (int i = blockIdx.x * 256 + threadIdx.x; i < n8; i += gridDim.x * 256) {
    const f32x4 a = *(const f32x4*)(src + i * 8);
    const f32x4 b = *(const f32x4*)(src + i * 8 + 4);
    bf16x8 o;
#pragma unroll
    for (int j = 0; j < 4; j++) { o[j] = (bf16)a[j]; o[4 + j] = (bf16)b[j]; }
    *(bf16x8*)(dst + i * 8) = o;
  }
}

struct ProjArgs {
  const bf16* W[4];
  const float* bias[4];
  void* out[4];
  int mode[4];     // 0: f32 row-major [M][N=2048]; 1: bf16 [B,H,S,D]; 2: bf16 [B,H,D,S]
  float scale[4];  // applied AFTER bias
};

// ---------------- 256x256 NT GEMM, BK=64 as 2 k-slices, counted-vmcnt pipeline ------
// LDS: [2 dbuf][2 kslice] x (A 256x32 + B 256x32) bf16 = 128 KiB.
// Rows are 64B = 4 x 16B slots; phys slot = logical ^ ((row>>1)&3). With this
// involution, any 8 consecutive lanes of a fragment ds_read_b128 hit 8 distinct
// (bank-half, slot) pairs = all 32 banks exactly once (conflict-free; the
// round-8 (row&3) variant covered only 16 banks -> 1.26e7 conflicts).
// Staged via global_load_lds (linear dest, inverse-swizzled source col).
// Schedule per tile t (dbuf d=t&1):
//   ph0: issue slice1(t+1) | ds_read kk0 | 32 MFMA | vmcnt(8) | s_barrier
//   ph1: issue slice0(t+2) | ds_read kk1 | 32 MFMA | vmcnt(8) | s_barrier
// Loads never drain below 8 in flight in steady state (T3+T4); each load gets
// ~1.5 tiles of MFMA cover. vmcnt ledger verified incl. prologue and tail.
__global__ __launch_bounds__(512, 2) void gemm256_kernel(
    const bf16* __restrict__ A, ProjArgs pa, int nbm, int nbn)
{
  __shared__ char LdsA[2 * 2 * 16384];
  __shared__ char LdsB[2 * 2 * 16384];

  const int nwg = gridDim.x;
  const int qch = nwg >> 3;
  const int wg = (blockIdx.x & 7) * qch + (blockIdx.x >> 3);
  const int bm = wg % nbm;
  const int rest = wg / nbm;
  const int bn = rest % nbn;
  const int z = rest / nbn;

  const bf16* __restrict__ W = pa.W[z];
  const float* __restrict__ bias = pa.bias[z];
  void* __restrict__ out = pa.out[z];
  const int mode = pa.mode[z];
  const float scale = pa.scale[z];

  const int tid = threadIdx.x;
  const int lane = tid & 63;
  const int w = tid >> 6;          // 0..7
  const int wr = w >> 2;           // 0..1 (M)
  const int wc = w & 3;            // 0..3 (N)
  const int g = lane >> 4, c = lane & 15;

  // staging source map: row rw = tid>>2 (and rw+128), phys slot tid&3,
  // inverse-swizzled logical slot = (tid&3) ^ ((rw>>1)&3)
  const int rw = tid >> 2;                              // 0..127
  const int sc = (((tid & 3) ^ ((rw >> 1) & 3))) * 8;   // source col (elems)
  const bf16* Asrc = A + (size_t)(bm * 256 + rw) * 2048 + sc;
  const bf16* Bsrc = W + (size_t)(bn * 256 + rw) * 2048 + sc;

  // stage slice s (32 cols) of K-tile T into dbuf T&1: 4 gload_lds/thread
  auto stage = [&](int T, int s) {
    const int q4 = ((T & 1) * 2 + s) * 16384;
    const int k0 = T * 64 + s * 32;
#pragma unroll
    for (int j = 0; j < 2; j++) {
      gload_lds16(Asrc + (size_t)(j * 128) * 2048 + k0, LdsA + q4 + j * 8192 + tid * 16);
      gload_lds16(Bsrc + (size_t)(j * 128) * 2048 + k0, LdsB + q4 + j * 8192 + tid * 16);
    }
  };

  f32x4 acc[8][4] = {};
  const int fsw = (c >> 1) & 3;    // read-side swizzle term (row>>1)&3 == (c>>1)&3

  // prologue: slice0(0), slice1(0), slice0(1); wait slice0(0) landed (12 -> 8)
  stage(0, 0); stage(0, 1); stage(1, 0);
  WAITV(8);
  __builtin_amdgcn_s_barrier();

  const int NT = 2048 / 64;   // 32
  for (int t = 0; t < NT; t++) {
    const int d = t & 1;
#pragma unroll
    for (int ph = 0; ph < 2; ph++) {
      // issue next staging first
      if (ph == 0) { if (t + 1 < NT) stage(t + 1, 1); }
      else         { if (t + 2 < NT) stage(t + 2, 0); }

      // fragment reads from [d][slice=ph]
      const char* Aq = LdsA + (d * 2 + ph) * 16384;
      const char* Bq = LdsB + (d * 2 + ph) * 16384;
      bf16x8 af[8], bfr[4];
#pragma unroll
      for (int n = 0; n < 4; n++) {
        const int row = wc * 64 + n * 16 + c;
        bfr[n] = *(const bf16x8*)(Bq + row * 64 + ((g ^ fsw) * 16));
      }
#pragma unroll
      for (int mi = 0; mi < 8; mi++) {
        const int row = wr * 128 + mi * 16 + c;
        af[mi] = *(const bf16x8*)(Aq + row * 64 + ((g ^ fsw) * 16));
      }
      __builtin_amdgcn_s_setprio(1);
#pragma unroll
      for (int mi = 0; mi < 8; mi++)
#pragma unroll
        for (int n = 0; n < 4; n++)
          acc[mi][n] = __builtin_amdgcn_mfma_f32_16x16x32_bf16(af[mi], bfr[n], acc[mi][n], 0, 0, 0);
      __builtin_amdgcn_s_setprio(0);

      // counted wait + barrier (never drain to 0 in steady state)
      if (ph == 0) {
        if (t == NT - 1) { WAITV(0); } else { WAITV(8); }
        __builtin_amdgcn_s_barrier();
      } else {
        if (t < NT - 2)       { WAITV(8); __builtin_amdgcn_s_barrier(); }
        else if (t == NT - 2) { WAITV(4); __builtin_amdgcn_s_barrier(); }
        // t == NT-1: loop ends
      }
    }
  }

  // epilogue: D[r][c]: col = lane&15, row = (lane>>4)*4 + j  (per 16x16 frag)
#pragma unroll
  for (int mi = 0; mi < 8; mi++) {
#pragma unroll
    for (int n = 0; n < 4; n++) {
      const int col = bn * 256 + wc * 64 + n * 16 + c;
      const float bv = bias[col];
#pragma unroll
      for (int j = 0; j < 4; j++) {
        const int row = bm * 256 + wr * 128 + mi * 16 + g * 4 + j;
        const float v = (acc[mi][n][j] + bv) * scale;
        if (mode == 0) {
          ((float*)out)[(size_t)row * E_DIM + col] = v;
        } else {
          const int b = row >> 11, s = row & 2047;
          const int h = col >> 7, d2 = col & 127;
          size_t idx;
          if (mode == 1) idx = (((size_t)(b * HEADS + h)) * SEQ + s) * HD + d2;
          else           idx = (((size_t)(b * HEADS + h)) * HD + d2) * SEQ + s;
          ((bf16*)out)[idx] = (bf16)v;
        }
      }
    }
  }
}

// ---------------- 128x128 NT GEMM (round-3 version) for the final projection ----------
__global__ __launch_bounds__(256) void gemm_nt_kernel(
    const bf16* __restrict__ A, ProjArgs pa, int M, int N, int K)
{
  __shared__ bf16 As[2][128 * 32];
  __shared__ bf16 Bs[2][128 * 32];

  const int z = blockIdx.z;
  const bf16* __restrict__ W = pa.W[z];
  const float* __restrict__ bias = pa.bias[z];
  void* __restrict__ out = pa.out[z];
  const int mode = pa.mode[z];
  const float scale = pa.scale[z];

  const int tid = threadIdx.x;
  const int lane = tid & 63;
  const int w = tid >> 6;
  const int wr = w >> 1, wc = w & 1;
  const int g = lane >> 4, c = lane & 15;
  const int bm = blockIdx.x, bn = blockIdx.y;

  f32x4 acc[4][4] = {};

  const int srow = lane >> 2;          // 0..15
  const int scol = (lane & 3) * 8;     // 0,8,16,24
  const bf16* Ab = A + (size_t)(bm * 128 + srow) * K + scol;
  const bf16* Wb = W + (size_t)(bn * 128 + srow) * K + scol;

  auto stage = [&](int k0, int buf) {
#pragma unroll
    for (int i = 0; i < 2; ++i) {
      const int chunk = w * 2 + i;     // 0..7, each 1024B = 16 rows x 32 cols
      gload_lds16(Ab + (size_t)(chunk * 16) * K + k0, (char*)(&As[buf][0]) + chunk * 1024);
      gload_lds16(Wb + (size_t)(chunk * 16) * K + k0, (char*)(&Bs[buf][0]) + chunk * 1024);
    }
  };

  stage(0, 0);
  __syncthreads();
  int cur = 0;

  for (int k0 = 0; k0 < K; k0 += 32) {
    if (k0 + 32 < K) stage(k0 + 32, cur ^ 1);
    bf16x8 af[4], bfr[4];
#pragma unroll
    for (int m = 0; m < 4; m++)
      af[m] = *(const bf16x8*)(&As[cur][0] + (wr * 64 + m * 16 + c) * 32 + g * 8);
#pragma unroll
    for (int n = 0; n < 4; n++)
      bfr[n] = *(const bf16x8*)(&Bs[cur][0] + (wc * 64 + n * 16 + c) * 32 + g * 8);
#pragma unroll
    for (int m = 0; m < 4; m++)
#pragma unroll
      for (int n = 0; n < 4; n++)
        acc[m][n] = __builtin_amdgcn_mfma_f32_16x16x32_bf16(af[m], bfr[n], acc[m][n], 0, 0, 0);
    __syncthreads();
    cur ^= 1;
  }

#pragma unroll
  for (int m = 0; m < 4; m++) {
#pragma unroll
    for (int n = 0; n < 4; n++) {
      const int col = bn * 128 + wc * 64 + n * 16 + c;
      const float bv = bias[col];
#pragma unroll
      for (int j = 0; j < 4; j++) {
        const int row = bm * 128 + wr * 64 + m * 16 + g * 4 + j;
        const float v = (acc[m][n][j] + bv) * scale;
        if (mode == 0) {
          ((float*)out)[(size_t)row * N + col] = v;
        } else {
          const int b = row >> 11, s = row & 2047;
          const int h = col >> 7, d = col & 127;
          size_t idx;
          if (mode == 1) idx = (((size_t)(b * HEADS + h)) * SEQ + s) * HD + d;
          else           idx = (((size_t)(b * HEADS + h)) * HD + d) * SEQ + s;
          ((bf16*)out)[idx] = (bf16)v;
        }
      }
    }
  }
}

// ---------------- slots projections: tk/tv = slots @ W^T + b, f32 [8][2048] ----------------
__global__ __launch_bounds__(256) void slots_proj_kernel(
    const float* __restrict__ slots,
    const float* __restrict__ Wk, const float* __restrict__ bk,
    const float* __restrict__ Wv, const float* __restrict__ bv,
    float* __restrict__ tk, float* __restrict__ tv)
{
  const int col = blockIdx.x * 256 + threadIdx.x;
  const int slot = blockIdx.y;
  const int mat = blockIdx.z;
  const float* W = mat ? Wv : Wk;
  const float* bias = mat ? bv : bk;
  float* out = mat ? tv : tk;
  const float* xr = slots + (size_t)slot * E_DIM;
  const float* wr = W + (size_t)col * E_DIM;
  float acc = 0.f;
  for (int k = 0; k < E_DIM; k += 4) {
    const f32x4 a = *(const f32x4*)(xr + k);
    const f32x4 b4 = *(const f32x4*)(wr + k);
#pragma unroll
    for (int i = 0; i < 4; i++) acc += a[i] * b4[i];
  }
  out[(size_t)slot * E_DIM + col] = acc + bias[col];
}

// ---------------- flash attention: 8-wave 32x32 MFMA, in-register softmax ----------------
// (round-7 measured-good version, verbatim)
__global__ __launch_bounds__(512) void flash_attn_kernel(
    const bf16* __restrict__ Qg, const bf16* __restrict__ Kg,
    const bf16* __restrict__ Vtg, bf16* __restrict__ Og)
{
  __shared__ char Ks[2][64 * 256];    // [kv][d] bf16, 256B rows, slot ^= r&15
  __shared__ char Vs[2][128 * 128];   // [d][kv] bf16, 128B rows, slot ^= r&7

  const int orig = blockIdx.x;                 // 256 blocks
  const int logical = (orig & 7) * 32 + (orig >> 3);   // XCD k -> bh in [4k,4k+4)
  const int qt = logical & 7;
  const int bh = logical >> 3;

  const int tid = threadIdx.x;
  const int lane = tid & 63;
  const int w = tid >> 6;          // 0..7
  const int q = lane & 31;
  const int hi = lane >> 5;
  const int b = bh >> 4, h = bh & 15;
  const int q0 = qt * 256 + w * 32;

  const bf16* Qb = Qg + ((size_t)bh * SEQ + q0) * HD;
  const bf16* Kb = Kg + (size_t)bh * SEQ * HD;
  const bf16* Vb = Vtg + (size_t)bh * HD * SEQ;

  // staging: 512 threads x (2 K-chunks + 2 V-chunks) x 16B = 16KB K + 16KB V
  auto stage = [&](int kv0, int buf) {
#pragma unroll
    for (int i = 0; i < 2; i++) {
      const int p = (tid + i * 512) * 16;
      { const int r = p >> 8; const int s16 = (p >> 4) & 15;
        gload_lds16(Kb + (size_t)(kv0 + r) * HD + (s16 ^ (r & 15)) * 8, &Ks[buf][0] + p); }
      { const int r = p >> 7; const int s8 = (p >> 4) & 7;
        gload_lds16(Vb + (size_t)r * SEQ + kv0 + (s8 ^ (r & 7)) * 8, &Vs[buf][0] + p); }
    }
  };

  // Q B-operand fragments: qf[kc][j] = Q[q][kc*16 + 8*hi + j]
  bf16x8 qf[8];
#pragma unroll
  for (int kc = 0; kc < 8; kc++)
    qf[kc] = *(const bf16x8*)(Qb + (size_t)q * HD + kc * 16 + hi * 8);

  stage(0, 0);
  __syncthreads();
  int cur = 0;

  f32x16 o[4] = {};                  // O^T[d][q], 4 d-blocks of 32
  float mrun = -1e30f, lsum = 0.f;

  for (int kv0 = 0; kv0 < SEQ; kv0 += 64) {
    if (kv0 + 64 < SEQ) stage(kv0 + 64, cur ^ 1);

    // S^T[kv][q] = K · Q^T, two 32-kv blocks
    f32x16 st[2] = {};
    __builtin_amdgcn_s_setprio(1);
#pragma unroll
    for (int kc = 0; kc < 8; kc++) {
#pragma unroll
      for (int blk = 0; blk < 2; blk++) {
        const int rt = blk * 32 + q;
        const int sl = (2 * kc + hi) ^ (rt & 15);
        const bf16x8 kf = *(const bf16x8*)(&Ks[cur][0] + rt * 256 + sl * 16);
        st[blk] = __builtin_amdgcn_mfma_f32_32x32x16_bf16(kf, qf[kc], st[blk], 0, 0, 0);
      }
    }
    __builtin_amdgcn_s_setprio(0);

    // softmax: one q per lane; 32 local kv + the 32 in lane^32
    float t[16];
#pragma unroll
    for (int i = 0; i < 16; i++) t[i] = fmaxf(st[0][i], st[1][i]);
#pragma unroll
    for (int s2 = 8; s2 > 0; s2 >>= 1)
#pragma unroll
      for (int i = 0; i < 8; i++) if (i < s2) t[i] = fmaxf(t[i], t[i + s2]);
    float lm = t[0];
    lm = fmaxf(lm, __shfl_xor(lm, 32));

    float fsc = 1.0f;
    if (__any(lm > mrun + 8.0f)) {             // defer-max (T13), wave-uniform
      const float mn = fmaxf(mrun, lm);
      fsc = exp2f(mrun - mn);
      mrun = mn;
#pragma unroll
      for (int db = 0; db < 4; db++)
#pragma unroll
        for (int i = 0; i < 16; i++) o[db][i] *= fsc;
    }

    float ps0 = 0.f, ps1 = 0.f, ps2 = 0.f, ps3 = 0.f;
#pragma unroll
    for (int blk = 0; blk < 2; blk++)
#pragma unroll
      for (int i = 0; i < 16; i += 4) {
        const float p0 = exp2f(st[blk][i]     - mrun);
        const float p1 = exp2f(st[blk][i + 1] - mrun);
        const float p2 = exp2f(st[blk][i + 2] - mrun);
        const float p3 = exp2f(st[blk][i + 3] - mrun);
        st[blk][i] = p0; st[blk][i + 1] = p1; st[blk][i + 2] = p2; st[blk][i + 3] = p3;
        ps0 += p0; ps1 += p1; ps2 += p2; ps3 += p3;
      }
    lsum = lsum * fsc + ((ps0 + ps1) + (ps2 + ps3));

    // P (C-layout) -> PV B-operand fragments via 2 shfl_xor(32) per 16-kv chunk
    bf16x8 pb[2][2];
#pragma unroll
    for (int blk = 0; blk < 2; blk++)
#pragma unroll
      for (int c2 = 0; c2 < 2; c2++) {
        bf16x4 Lv, Hv;
#pragma unroll
        for (int i = 0; i < 4; i++) {
          Lv[i] = (bf16)st[blk][8 * c2 + i];
          Hv[i] = (bf16)st[blk][8 * c2 + 4 + i];
        }
        const u32x2 Lu = __builtin_bit_cast(u32x2, Lv);
        const u32x2 Hu = __builtin_bit_cast(u32x2, Hv);
        const uint32_t s0 = hi ? Lu.x : Hu.x;     // half1 sends L, half0 sends H
        const uint32_t s1 = hi ? Lu.y : Hu.y;
        const uint32_t x0 = (uint32_t)__shfl_xor((int)s0, 32);
        const uint32_t x1 = (uint32_t)__shfl_xor((int)s1, 32);
        u32x4 bv;
        bv.x = hi ? x0 : Lu.x;
        bv.y = hi ? x1 : Lu.y;
        bv.z = hi ? Hu.x : x0;
        bv.w = hi ? Hu.y : x1;
        pb[blk][c2] = __builtin_bit_cast(bf16x8, bv);
      }

    // O^T[d][q] += V^T[d][kv] · P^T[kv][q]
    __builtin_amdgcn_s_setprio(1);
#pragma unroll
    for (int db = 0; db < 4; db++) {
      const int rt = db * 32 + q;
#pragma unroll
      for (int blk = 0; blk < 2; blk++)
#pragma unroll
        for (int c2 = 0; c2 < 2; c2++) {
          const int sl = (blk * 4 + c2 * 2 + hi) ^ (rt & 7);
          const bf16x8 vf = *(const bf16x8*)(&Vs[cur][0] + rt * 128 + sl * 16);
          o[db] = __builtin_amdgcn_mfma_f32_32x32x16_bf16(vf, pb[blk][c2], o[db], 0, 0, 0);
        }
    }
    __builtin_amdgcn_s_setprio(0);

    __syncthreads();   // drains own staging vmcnt; guards dbuf reuse
    cur ^= 1;
  }

  // epilogue: total l = own + other half; per-lane normalize; vec4 stores
  const float lt = lsum + __shfl_xor(lsum, 32);
  const float linv = 1.0f / lt;
  bf16* Orow = Og + ((size_t)b * SEQ + q0 + q) * E_DIM + h * HD;
#pragma unroll
  for (int db = 0; db < 4; db++)
#pragma unroll
    for (int g4 = 0; g4 < 4; g4++) {
      bf16x4 ov;
#pragma unroll
      for (int i = 0; i < 4; i++) ov[i] = (bf16)(o[db][g4 * 4 + i] * linv);
      *(bf16x4*)(Orow + db * 32 + g4 * 8 + hi * 4) = ov;
    }
}

// ---------------- fused thought cross-attn + LayerNorm ----------------
__global__ __launch_bounds__(256) void thought_ln_kernel(
    const bf16* __restrict__ TQ, const float* __restrict__ TK,
    const float* __restrict__ TV, const bf16* __restrict__ ATT,
    const float* __restrict__ gamma, const float* __restrict__ beta,
    bf16* __restrict__ Y)
{
  __shared__ float wsum[4], wsq[4];
  const int tid = threadIdx.x;
  const int lane = tid & 63;
  const int w = tid >> 6;
  const int tok = blockIdx.x;            // b*SEQ + s
  const int b = tok >> 11, s = tok & 2047;
  const int e0 = tid * 8;
  const int h = e0 >> 7;
  const int d0 = e0 & 127;

  const bf16x8 av = *(const bf16x8*)(ATT + (size_t)tok * E_DIM + e0);
  float v[8];
#pragma unroll
  for (int i = 0; i < 8; i++) v[i] = (float)av[i];

  const bf16x8 qv8 = *(const bf16x8*)(TQ + (((size_t)(b * HEADS + h)) * SEQ + s) * HD + d0);
  float qv[8];
#pragma unroll
  for (int i = 0; i < 8; i++) qv[i] = (float)qv8[i];

  float dts[NSLOT];
#pragma unroll
  for (int sl = 0; sl < NSLOT; sl++) {
    const float* tkr = TK + (size_t)sl * E_DIM + e0;
    const f32x4 k0 = *(const f32x4*)(tkr);
    const f32x4 k1 = *(const f32x4*)(tkr + 4);
    float dp = 0.f;
#pragma unroll
    for (int i = 0; i < 4; i++) dp += qv[i] * k0[i] + qv[4 + i] * k1[i];
    dp += __shfl_xor(dp, 1);
    dp += __shfl_xor(dp, 2);
    dp += __shfl_xor(dp, 4);
    dp += __shfl_xor(dp, 8);
    dts[sl] = dp;
  }
  float mx = dts[0];
#pragma unroll
  for (int sl = 1; sl < NSLOT; sl++) mx = fmaxf(mx, dts[sl]);
  float p[NSLOT], den = 0.f;
#pragma unroll
  for (int sl = 0; sl < NSLOT; sl++) { p[sl] = exp2f(dts[sl] - mx); den += p[sl]; }
  const float dinv = 1.0f / den;
#pragma unroll
  for (int sl = 0; sl < NSLOT; sl++) {
    const float pn = p[sl] * dinv;
    const float* tvr = TV + (size_t)sl * E_DIM + e0;
    const f32x4 v0 = *(const f32x4*)(tvr);
    const f32x4 v1 = *(const f32x4*)(tvr + 4);
#pragma unroll
    for (int i = 0; i < 4; i++) { v[i] += pn * v0[i]; v[4 + i] += pn * v1[i]; }
  }

  float sm = 0.f, sq = 0.f;
#pragma unroll
  for (int i = 0; i < 8; i++) { sm += v[i]; sq += v[i] * v[i]; }
#pragma unroll
  for (int d = 1; d < 64; d <<= 1) { sm += __shfl_xor(sm, d); sq += __shfl_xor(sq, d); }
  if (lane == 0) { wsum[w] = sm; wsq[w] = sq; }
  __syncthreads();
  const float ts = wsum[0] + wsum[1] + wsum[2] + wsum[3];
  const float tq2 = wsq[0] + wsq[1] + wsq[2] + wsq[3];
  const float mean = ts * (1.f / E_DIM);
  const float var = tq2 * (1.f / E_DIM) - mean * mean;
  const float rstd = rsqrtf(var + 1e-5f);
  const f32x4 g0 = *(const f32x4*)(gamma + e0);
  const f32x4 g1 = *(const f32x4*)(gamma + e0 + 4);
  const f32x4 b0 = *(const f32x4*)(beta + e0);
  const f32x4 b1 = *(const f32x4*)(beta + e0 + 4);
  bf16x8 outv;
#pragma unroll
  for (int i = 0; i < 4; i++) {
    outv[i]     = (bf16)((v[i]     - mean) * rstd * g0[i] + b0[i]);
    outv[4 + i] = (bf16)((v[4 + i] - mean) * rstd * g1[i] + b1[i]);
  }
  *(bf16x8*)(Y + (size_t)tok * E_DIM + e0) = outv;
}

extern "C" void kernel_launch(void* const* d_in, const int* in_sizes, int n_in,
                              void* d_out, int out_size, void* d_ws, size_t ws_size,
                              hipStream_t stream) {
  (void)in_sizes; (void)n_in; (void)out_size; (void)ws_size;
  const float* x     = (const float*)d_in[0];
  const float* slots = (const float*)d_in[1];
  const float* Wq  = (const float*)d_in[2];   const float* bq  = (const float*)d_in[3];
  const float* Wk  = (const float*)d_in[4];   const float* bk  = (const float*)d_in[5];
  const float* Wv  = (const float*)d_in[6];   const float* bv  = (const float*)d_in[7];
  const float* Wtq = (const float*)d_in[8];   const float* btq = (const float*)d_in[9];
  const float* Wtk = (const float*)d_in[10];  const float* btk = (const float*)d_in[11];
  const float* Wtv = (const float*)d_in[12];  const float* btv = (const float*)d_in[13];
  const float* Wo  = (const float*)d_in[14];  const float* bo  = (const float*)d_in[15];
  const float* gamma = (const float*)d_in[16];
  const float* beta  = (const float*)d_in[17];

  uint8_t* ws = (uint8_t*)d_ws;
  const size_t BUF  = (size_t)NTOK * E_DIM * sizeof(bf16);    // 16 MiB (activations)
  const size_t WBUF = (size_t)E_DIM * E_DIM * sizeof(bf16);   // 8 MiB (weights)
  bf16* xb   = (bf16*)(ws + 0 * BUF);          // [B,S,E] bf16 x
  bf16* qb   = (bf16*)(ws + 1 * BUF);          // [B,H,S,D] (pre-scaled)
  bf16* kb   = (bf16*)(ws + 2 * BUF);          // [B,H,S,D]
  bf16* vtb  = (bf16*)(ws + 3 * BUF);          // [B,H,D,S]
  bf16* tqb  = (bf16*)(ws + 4 * BUF);          // [B,H,S,D] (pre-scaled)
  bf16* attb = (bf16*)(ws + 5 * BUF);          // [B,S,E] flash output
  bf16* nrmb = qb;                             // alias: qb dead after flash
  uint8_t* wp = ws + 6 * BUF;
  bf16* Wqb  = (bf16*)(wp + 0 * WBUF);
  bf16* Wkb  = (bf16*)(wp + 1 * WBUF);
  bf16* Wvb  = (bf16*)(wp + 2 * WBUF);
  bf16* Wtqb = (bf16*)(wp + 3 * WBUF);
  bf16* Wob  = (bf16*)(wp + 4 * WBUF);
  float* tkb = (float*)(wp + 5 * WBUF);               // [8][E] f32
  float* tvb = (float*)(wp + 5 * WBUF + 128 * 1024);  // [8][E] f32

  // --- convert f32 -> bf16 for MFMA consumers ---
  const int WN8 = E_DIM * E_DIM / 8;   // 524288
  const int XN8 = NTOK * E_DIM / 8;    // 1048576
  cvt_f32_bf16_kernel<<<dim3(2048), 256, 0, stream>>>(x, xb, XN8);
  cvt_f32_bf16_kernel<<<dim3(1024), 256, 0, stream>>>(Wq, Wqb, WN8);
  cvt_f32_bf16_kernel<<<dim3(1024), 256, 0, stream>>>(Wk, Wkb, WN8);
  cvt_f32_bf16_kernel<<<dim3(1024), 256, 0, stream>>>(Wv, Wvb, WN8);
  cvt_f32_bf16_kernel<<<dim3(1024), 256, 0, stream>>>(Wtq, Wtqb, WN8);
  cvt_f32_bf16_kernel<<<dim3(1024), 256, 0, stream>>>(Wo, Wob, WN8);

  // --- projections (Q and TQ pre-scaled by 1/sqrt(D)*log2e) ---
  ProjArgs pa;
  pa.W[0] = Wqb;  pa.bias[0] = bq;  pa.out[0] = qb;  pa.mode[0] = 1; pa.scale[0] = QSCALE;
  pa.W[1] = Wkb;  pa.bias[1] = bk;  pa.out[1] = kb;  pa.mode[1] = 1; pa.scale[1] = 1.0f;
  pa.W[2] = Wvb;  pa.bias[2] = bv;  pa.out[2] = vtb; pa.mode[2] = 2; pa.scale[2] = 1.0f;
  pa.W[3] = Wtqb; pa.bias[3] = btq; pa.out[3] = tqb; pa.mode[3] = 1; pa.scale[3] = QSCALE;
  gemm256_kernel<<<dim3(16 * 8 * 4), 512, 0, stream>>>(xb, pa, 16, 8);

  slots_proj_kernel<<<dim3(E_DIM / 256, NSLOT, 2), 256, 0, stream>>>(
      slots, Wtk, btk, Wtv, btv, tkb, tvb);

  // --- attention streams ---
  flash_attn_kernel<<<dim3((SEQ / 256) * BATCH * HEADS), 512, 0, stream>>>(
      qb, kb, vtb, attb);
  thought_ln_kernel<<<dim3(NTOK), 256, 0, stream>>>(
      tqb, tkb, tvb, attb, gamma, beta, nrmb);

  // --- output projection (f32 out), 128^2 tiles: 512 blocks = 2/CU ---
  ProjArgs po;
  po.W[0] = Wob; po.bias[0] = bo; po.out[0] = d_out; po.mode[0] = 0; po.scale[0] = 1.0f;
  po.W[1] = po.W[2] = po.W[3] = Wob;
  po.bias[1] = po.bias[2] = po.bias[3] = bo;
  po.out[1] = po.out[2] = po.out[3] = d_out;
  po.mode[1] = po.mode[2] = po.mode[3] = 0;
  po.scale[1] = po.scale[2] = po.scale[3] = 1.0f;
  gemm_nt_kernel<<<dim3(NTOK / 128, E_DIM / 128, 1), 256, 0, stream>>>(
      nrmb, po, NTOK, E_DIM, E_DIM);
}

// Round 10
// 466.107 us; speedup vs baseline: 1.1785x; 1.0350x over previous
//
#include <hip/hip_runtime.h>
#include <hip/hip_bf16.h>
#include <stdint.h>

typedef __bf16 bf16;
typedef __bf16 bf16x8 __attribute__((ext_vector_type(8)));
typedef __bf16 bf16x4 __attribute__((ext_vector_type(4)));
typedef float f32x4 __attribute__((ext_vector_type(4)));
typedef float f32x16 __attribute__((ext_vector_type(16)));
typedef uint32_t u32x2 __attribute__((ext_vector_type(2)));
typedef uint32_t u32x4 __attribute__((ext_vector_type(4)));

#define E_DIM 2048
#define HEADS 16
#define HD 128
#define SEQ 2048
#define BATCH 2
#define NTOK 4096
#define NSLOT 8

// 1/sqrt(128) * log2(e): folded into Q / TQ at projection time
#define QSCALE (0.08838834764831845f * 1.4426950408889634f)

#define WAITV(N) asm volatile("s_waitcnt vmcnt(" #N ")" ::: "memory")

__device__ __forceinline__ void gload_lds16(const void* g, void* lds) {
  __builtin_amdgcn_global_load_lds(
      (const __attribute__((address_space(1))) uint32_t*)g,
      (__attribute__((address_space(3))) uint32_t*)lds, 16, 0, 0);
}

// ---------------- f32 -> bf16 convert, 8 elems/thread, grid-stride ----------------
__global__ __launch_bounds__(256) void cvt_f32_bf16_kernel(
    const float* __restrict__ src, bf16* __restrict__ dst, int n8)
{
  for (int i = blockIdx.x * 256 + threadIdx.x; i < n8; i += gridDim.x * 256) {
    const f32x4 a = *(const f32x4*)(src + i * 8);
    const f32x4 b = *(const f32x4*)(src + i * 8 + 4);
    bf16x8 o;
#pragma unroll
    for (int j = 0; j < 4; j++) { o[j] = (bf16)a[j]; o[4 + j] = (bf16)b[j]; }
    *(bf16x8*)(dst + i * 8) = o;
  }
}

struct ProjArgs {
  const bf16* W[4];
  const float* bias[4];
  void* out[4];
  int mode[4];     // 0: f32 row-major [M][N=2048]; 1: bf16 [B,H,S,D]; 2: bf16 [B,H,D,S]
  float scale[4];  // applied AFTER bias
};

// ---------------- 256x256 NT GEMM, 4-phase/K-tile, counted vmcnt(6), reg-held B -----
// BK=64, 8 waves (2M x 4N). LDS: As/Bs [2 dbuf][256 rows][64 cols] bf16 = 128 KiB.
// Rows = 128B = 8 x 16B slots; phys slot = logical ^ (row&7) (<=2-way reads, free).
// Per K-tile t (dbuf d=t&1), 4 phases q=0..3 (quadrant = mi {2q,2q+1}):
//   q0: ds_read B-all (8 x b128, HELD IN REGS for q0..q3) + A-quad (4)
//   q>0: ds_read A-quad (4)
//   s_barrier                      <- proves dying slab's readers done (all waves)
//   stage one 16KB unit (2 gload_lds/thread), stream:
//     q0: (t+1):A1   q1: (t+2):B0   q2: (t+2):B1   q3: (t+2):A0
//     (t+2 units write dbuf d into regions dead since a prior barrier:
//      B dead after q0, A rows 0..127 dead after q3's reads; (t+1):A1 is dbuf d^1)
//   setprio(1); 16 MFMA; setprio(0)
//   q3 only: vmcnt(6)  <- retires tile t+1's 4 units (3 units = 6 loads stay in
//            flight; NEVER drains to 0 in steady state). Tail: t==NT-2 -> vmcnt(0).
//   s_barrier
// Prologue stages 7 units (t0:B0,B1,A0,A1, t1:B0,B1,A0) then vmcnt(6).
// FIFO ledger + slab-death orderings verified; see round-10 notes.
__global__ __launch_bounds__(512, 2) void gemm256_kernel(
    const bf16* __restrict__ A, ProjArgs pa, int nbm, int nbn)
{
  __shared__ char As_[2 * 32768];
  __shared__ char Bs_[2 * 32768];

  const int nwg = gridDim.x;
  const int qch = nwg >> 3;
  const int wg = (blockIdx.x & 7) * qch + (blockIdx.x >> 3);
  const int bm = wg % nbm;
  const int rest = wg / nbm;
  const int bn = rest % nbn;
  const int z = rest / nbn;

  const bf16* __restrict__ W = pa.W[z];
  const float* __restrict__ bias = pa.bias[z];
  void* __restrict__ out = pa.out[z];
  const int mode = pa.mode[z];
  const float scale = pa.scale[z];

  const int tid = threadIdx.x;
  const int lane = tid & 63;
  const int w = tid >> 6;          // 0..7
  const int wr = w >> 2;           // 0..1 (M)
  const int wc = w & 3;            // 0..3 (N)
  const int g = lane >> 4, c = lane & 15;

  // staging map (per 16KB unit, 2 loads/thread):
  //   load j: row-in-unit = (tid>>3) + j*64, phys slot = tid&7
  //   inverse-swizzled source col = (slot ^ (row&7))*8  (row&7 == (tid>>3)&7)
  const int srow = tid >> 3;                       // 0..63
  const int sslot = tid & 7;
  const int scol = (sslot ^ (srow & 7)) * 8;
  const bf16* Abase = A + (size_t)(bm * 256) * 2048;
  const bf16* Bbase = W + (size_t)(bn * 256) * 2048;

  auto stageU = [&](const bf16* gbase, char* lds, int T, int u) {
    char* dst = lds + (T & 1) * 32768 + u * 16384;
    const int k0 = T * 64;
#pragma unroll
    for (int j = 0; j < 2; j++) {
      const int r = u * 128 + srow + j * 64;
      gload_lds16(gbase + (size_t)r * 2048 + k0 + scol,
                  dst + (size_t)(srow + j * 64) * 128 + sslot * 16);
    }
  };

  f32x4 acc[8][4] = {};
  bf16x8 bfr[4][2];                // B fragments, held across the 4 phases

  // prologue: units t0:B0,B1,A0,A1, t1:B0,B1,A0  (14 loads); retire t0 (vmcnt 6)
  stageU(Bbase, Bs_, 0, 0); stageU(Bbase, Bs_, 0, 1);
  stageU(Abase, As_, 0, 0); stageU(Abase, As_, 0, 1);
  stageU(Bbase, Bs_, 1, 0); stageU(Bbase, Bs_, 1, 1);
  stageU(Abase, As_, 1, 0);
  WAITV(6);
  __builtin_amdgcn_s_barrier();

  const int NT = 2048 / 64;        // 32
  for (int t = 0; t < NT; t++) {
    const int d = t & 1;
    const char* Aq = As_ + d * 32768;
    const char* Bq = Bs_ + d * 32768;
#pragma unroll
    for (int q = 0; q < 4; q++) {
      // --- ds_read (before barrier) ---
      bf16x8 af[2][2];
      if (q == 0) {
#pragma unroll
        for (int n = 0; n < 4; n++)
#pragma unroll
          for (int kk = 0; kk < 2; kk++) {
            const int row = wc * 64 + n * 16 + c;
            bfr[n][kk] = *(const bf16x8*)(Bq + (size_t)row * 128 +
                                          (((kk * 4 + g) ^ (c & 7)) * 16));
          }
      }
#pragma unroll
      for (int mi2 = 0; mi2 < 2; mi2++)
#pragma unroll
        for (int kk = 0; kk < 2; kk++) {
          const int row = wr * 128 + (q * 2 + mi2) * 16 + c;
          af[mi2][kk] = *(const bf16x8*)(Aq + (size_t)row * 128 +
                                         (((kk * 4 + g) ^ (c & 7)) * 16));
        }

      __builtin_amdgcn_s_barrier();   // orders dying-slab reads before stage below

      // --- stage one unit (stream; targets proven dead) ---
      if (q == 0)      { if (t + 1 < NT) stageU(Abase, As_, t + 1, 1); }
      else if (q == 1) { if (t + 2 < NT) stageU(Bbase, Bs_, t + 2, 0); }
      else if (q == 2) { if (t + 2 < NT) stageU(Bbase, Bs_, t + 2, 1); }
      else             { if (t + 2 < NT) stageU(Abase, As_, t + 2, 0); }

      // --- MFMA quadrant ---
      __builtin_amdgcn_s_setprio(1);
#pragma unroll
      for (int mi2 = 0; mi2 < 2; mi2++)
#pragma unroll
        for (int n = 0; n < 4; n++)
#pragma unroll
          for (int kk = 0; kk < 2; kk++)
            acc[q * 2 + mi2][n] = __builtin_amdgcn_mfma_f32_16x16x32_bf16(
                af[mi2][kk], bfr[n][kk], acc[q * 2 + mi2][n], 0, 0, 0);
      __builtin_amdgcn_s_setprio(0);

      // --- once-per-tile counted wait ---
      if (q == 3) {
        if (t < NT - 2)       { WAITV(6); }
        else if (t == NT - 2) { WAITV(0); }
      }
      __builtin_amdgcn_s_barrier();
    }
  }

  // epilogue: D[r][c]: col = lane&15, row = (lane>>4)*4 + j  (per 16x16 frag)
#pragma unroll
  for (int mi = 0; mi < 8; mi++) {
#pragma unroll
    for (int n = 0; n < 4; n++) {
      const int col = bn * 256 + wc * 64 + n * 16 + c;
      const float bv = bias[col];
#pragma unroll
      for (int j = 0; j < 4; j++) {
        const int row = bm * 256 + wr * 128 + mi * 16 + g * 4 + j;
        const float v = (acc[mi][n][j] + bv) * scale;
        if (mode == 0) {
          ((float*)out)[(size_t)row * E_DIM + col] = v;
        } else {
          const int b = row >> 11, s = row & 2047;
          const int h = col >> 7, d2 = col & 127;
          size_t idx;
          if (mode == 1) idx = (((size_t)(b * HEADS + h)) * SEQ + s) * HD + d2;
          else           idx = (((size_t)(b * HEADS + h)) * HD + d2) * SEQ + s;
          ((bf16*)out)[idx] = (bf16)v;
        }
      }
    }
  }
}

// ---------------- 128x128 NT GEMM (round-3 version) for the final projection ----------
__global__ __launch_bounds__(256) void gemm_nt_kernel(
    const bf16* __restrict__ A, ProjArgs pa, int M, int N, int K)
{
  __shared__ bf16 As[2][128 * 32];
  __shared__ bf16 Bs[2][128 * 32];

  const int z = blockIdx.z;
  const bf16* __restrict__ W = pa.W[z];
  const float* __restrict__ bias = pa.bias[z];
  void* __restrict__ out = pa.out[z];
  const int mode = pa.mode[z];
  const float scale = pa.scale[z];

  const int tid = threadIdx.x;
  const int lane = tid & 63;
  const int w = tid >> 6;
  const int wr = w >> 1, wc = w & 1;
  const int g = lane >> 4, c = lane & 15;
  const int bm = blockIdx.x, bn = blockIdx.y;

  f32x4 acc[4][4] = {};

  const int srow = lane >> 2;          // 0..15
  const int scol = (lane & 3) * 8;     // 0,8,16,24
  const bf16* Ab = A + (size_t)(bm * 128 + srow) * K + scol;
  const bf16* Wb = W + (size_t)(bn * 128 + srow) * K + scol;

  auto stage = [&](int k0, int buf) {
#pragma unroll
    for (int i = 0; i < 2; ++i) {
      const int chunk = w * 2 + i;     // 0..7, each 1024B = 16 rows x 32 cols
      gload_lds16(Ab + (size_t)(chunk * 16) * K + k0, (char*)(&As[buf][0]) + chunk * 1024);
      gload_lds16(Wb + (size_t)(chunk * 16) * K + k0, (char*)(&Bs[buf][0]) + chunk * 1024);
    }
  };

  stage(0, 0);
  __syncthreads();
  int cur = 0;

  for (int k0 = 0; k0 < K; k0 += 32) {
    if (k0 + 32 < K) stage(k0 + 32, cur ^ 1);
    bf16x8 af[4], bfr[4];
#pragma unroll
    for (int m = 0; m < 4; m++)
      af[m] = *(const bf16x8*)(&As[cur][0] + (wr * 64 + m * 16 + c) * 32 + g * 8);
#pragma unroll
    for (int n = 0; n < 4; n++)
      bfr[n] = *(const bf16x8*)(&Bs[cur][0] + (wc * 64 + n * 16 + c) * 32 + g * 8);
#pragma unroll
    for (int m = 0; m < 4; m++)
#pragma unroll
      for (int n = 0; n < 4; n++)
        acc[m][n] = __builtin_amdgcn_mfma_f32_16x16x32_bf16(af[m], bfr[n], acc[m][n], 0, 0, 0);
    __syncthreads();
    cur ^= 1;
  }

#pragma unroll
  for (int m = 0; m < 4; m++) {
#pragma unroll
    for (int n = 0; n < 4; n++) {
      const int col = bn * 128 + wc * 64 + n * 16 + c;
      const float bv = bias[col];
#pragma unroll
      for (int j = 0; j < 4; j++) {
        const int row = bm * 128 + wr * 64 + m * 16 + g * 4 + j;
        const float v = (acc[m][n][j] + bv) * scale;
        if (mode == 0) {
          ((float*)out)[(size_t)row * N + col] = v;
        } else {
          const int b = row >> 11, s = row & 2047;
          const int h = col >> 7, d = col & 127;
          size_t idx;
          if (mode == 1) idx = (((size_t)(b * HEADS + h)) * SEQ + s) * HD + d;
          else           idx = (((size_t)(b * HEADS + h)) * HD + d) * SEQ + s;
          ((bf16*)out)[idx] = (bf16)v;
        }
      }
    }
  }
}

// ---------------- slots projections: tk/tv = slots @ W^T + b, f32 [8][2048] ----------------
__global__ __launch_bounds__(256) void slots_proj_kernel(
    const float* __restrict__ slots,
    const float* __restrict__ Wk, const float* __restrict__ bk,
    const float* __restrict__ Wv, const float* __restrict__ bv,
    float* __restrict__ tk, float* __restrict__ tv)
{
  const int col = blockIdx.x * 256 + threadIdx.x;
  const int slot = blockIdx.y;
  const int mat = blockIdx.z;
  const float* W = mat ? Wv : Wk;
  const float* bias = mat ? bv : bk;
  float* out = mat ? tv : tk;
  const float* xr = slots + (size_t)slot * E_DIM;
  const float* wr = W + (size_t)col * E_DIM;
  float acc = 0.f;
  for (int k = 0; k < E_DIM; k += 4) {
    const f32x4 a = *(const f32x4*)(xr + k);
    const f32x4 b4 = *(const f32x4*)(wr + k);
#pragma unroll
    for (int i = 0; i < 4; i++) acc += a[i] * b4[i];
  }
  out[(size_t)slot * E_DIM + col] = acc + bias[col];
}

// ---------------- flash attention: 8-wave 32x32 MFMA, in-register softmax ----------------
// (round-7 measured-good version, verbatim)
__global__ __launch_bounds__(512) void flash_attn_kernel(
    const bf16* __restrict__ Qg, const bf16* __restrict__ Kg,
    const bf16* __restrict__ Vtg, bf16* __restrict__ Og)
{
  __shared__ char Ks[2][64 * 256];    // [kv][d] bf16, 256B rows, slot ^= r&15
  __shared__ char Vs[2][128 * 128];   // [d][kv] bf16, 128B rows, slot ^= r&7

  const int orig = blockIdx.x;                 // 256 blocks
  const int logical = (orig & 7) * 32 + (orig >> 3);   // XCD k -> bh in [4k,4k+4)
  const int qt = logical & 7;
  const int bh = logical >> 3;

  const int tid = threadIdx.x;
  const int lane = tid & 63;
  const int w = tid >> 6;          // 0..7
  const int q = lane & 31;
  const int hi = lane >> 5;
  const int b = bh >> 4, h = bh & 15;
  const int q0 = qt * 256 + w * 32;

  const bf16* Qb = Qg + ((size_t)bh * SEQ + q0) * HD;
  const bf16* Kb = Kg + (size_t)bh * SEQ * HD;
  const bf16* Vb = Vtg + (size_t)bh * HD * SEQ;

  // staging: 512 threads x (2 K-chunks + 2 V-chunks) x 16B = 16KB K + 16KB V
  auto stage = [&](int kv0, int buf) {
#pragma unroll
    for (int i = 0; i < 2; i++) {
      const int p = (tid + i * 512) * 16;
      { const int r = p >> 8; const int s16 = (p >> 4) & 15;
        gload_lds16(Kb + (size_t)(kv0 + r) * HD + (s16 ^ (r & 15)) * 8, &Ks[buf][0] + p); }
      { const int r = p >> 7; const int s8 = (p >> 4) & 7;
        gload_lds16(Vb + (size_t)r * SEQ + kv0 + (s8 ^ (r & 7)) * 8, &Vs[buf][0] + p); }
    }
  };

  // Q B-operand fragments: qf[kc][j] = Q[q][kc*16 + 8*hi + j]
  bf16x8 qf[8];
#pragma unroll
  for (int kc = 0; kc < 8; kc++)
    qf[kc] = *(const bf16x8*)(Qb + (size_t)q * HD + kc * 16 + hi * 8);

  stage(0, 0);
  __syncthreads();
  int cur = 0;

  f32x16 o[4] = {};                  // O^T[d][q], 4 d-blocks of 32
  float mrun = -1e30f, lsum = 0.f;

  for (int kv0 = 0; kv0 < SEQ; kv0 += 64) {
    if (kv0 + 64 < SEQ) stage(kv0 + 64, cur ^ 1);

    // S^T[kv][q] = K · Q^T, two 32-kv blocks
    f32x16 st[2] = {};
    __builtin_amdgcn_s_setprio(1);
#pragma unroll
    for (int kc = 0; kc < 8; kc++) {
#pragma unroll
      for (int blk = 0; blk < 2; blk++) {
        const int rt = blk * 32 + q;
        const int sl = (2 * kc + hi) ^ (rt & 15);
        const bf16x8 kf = *(const bf16x8*)(&Ks[cur][0] + rt * 256 + sl * 16);
        st[blk] = __builtin_amdgcn_mfma_f32_32x32x16_bf16(kf, qf[kc], st[blk], 0, 0, 0);
      }
    }
    __builtin_amdgcn_s_setprio(0);

    // softmax: one q per lane; 32 local kv + the 32 in lane^32
    float t[16];
#pragma unroll
    for (int i = 0; i < 16; i++) t[i] = fmaxf(st[0][i], st[1][i]);
#pragma unroll
    for (int s2 = 8; s2 > 0; s2 >>= 1)
#pragma unroll
      for (int i = 0; i < 8; i++) if (i < s2) t[i] = fmaxf(t[i], t[i + s2]);
    float lm = t[0];
    lm = fmaxf(lm, __shfl_xor(lm, 32));

    float fsc = 1.0f;
    if (__any(lm > mrun + 8.0f)) {             // defer-max (T13), wave-uniform
      const float mn = fmaxf(mrun, lm);
      fsc = exp2f(mrun - mn);
      mrun = mn;
#pragma unroll
      for (int db = 0; db < 4; db++)
#pragma unroll
        for (int i = 0; i < 16; i++) o[db][i] *= fsc;
    }

    float ps0 = 0.f, ps1 = 0.f, ps2 = 0.f, ps3 = 0.f;
#pragma unroll
    for (int blk = 0; blk < 2; blk++)
#pragma unroll
      for (int i = 0; i < 16; i += 4) {
        const float p0 = exp2f(st[blk][i]     - mrun);
        const float p1 = exp2f(st[blk][i + 1] - mrun);
        const float p2 = exp2f(st[blk][i + 2] - mrun);
        const float p3 = exp2f(st[blk][i + 3] - mrun);
        st[blk][i] = p0; st[blk][i + 1] = p1; st[blk][i + 2] = p2; st[blk][i + 3] = p3;
        ps0 += p0; ps1 += p1; ps2 += p2; ps3 += p3;
      }
    lsum = lsum * fsc + ((ps0 + ps1) + (ps2 + ps3));

    // P (C-layout) -> PV B-operand fragments via 2 shfl_xor(32) per 16-kv chunk
    bf16x8 pb[2][2];
#pragma unroll
    for (int blk = 0; blk < 2; blk++)
#pragma unroll
      for (int c2 = 0; c2 < 2; c2++) {
        bf16x4 Lv, Hv;
#pragma unroll
        for (int i = 0; i < 4; i++) {
          Lv[i] = (bf16)st[blk][8 * c2 + i];
          Hv[i] = (bf16)st[blk][8 * c2 + 4 + i];
        }
        const u32x2 Lu = __builtin_bit_cast(u32x2, Lv);
        const u32x2 Hu = __builtin_bit_cast(u32x2, Hv);
        const uint32_t s0 = hi ? Lu.x : Hu.x;     // half1 sends L, half0 sends H
        const uint32_t s1 = hi ? Lu.y : Hu.y;
        const uint32_t x0 = (uint32_t)__shfl_xor((int)s0, 32);
        const uint32_t x1 = (uint32_t)__shfl_xor((int)s1, 32);
        u32x4 bv;
        bv.x = hi ? x0 : Lu.x;
        bv.y = hi ? x1 : Lu.y;
        bv.z = hi ? Hu.x : x0;
        bv.w = hi ? Hu.y : x1;
        pb[blk][c2] = __builtin_bit_cast(bf16x8, bv);
      }

    // O^T[d][q] += V^T[d][kv] · P^T[kv][q]
    __builtin_amdgcn_s_setprio(1);
#pragma unroll
    for (int db = 0; db < 4; db++) {
      const int rt = db * 32 + q;
#pragma unroll
      for (int blk = 0; blk < 2; blk++)
#pragma unroll
        for (int c2 = 0; c2 < 2; c2++) {
          const int sl = (blk * 4 + c2 * 2 + hi) ^ (rt & 7);
          const bf16x8 vf = *(const bf16x8*)(&Vs[cur][0] + rt * 128 + sl * 16);
          o[db] = __builtin_amdgcn_mfma_f32_32x32x16_bf16(vf, pb[blk][c2], o[db], 0, 0, 0);
        }
    }
    __builtin_amdgcn_s_setprio(0);

    __syncthreads();   // drains own staging vmcnt; guards dbuf reuse
    cur ^= 1;
  }

  // epilogue: total l = own + other half; per-lane normalize; vec4 stores
  const float lt = lsum + __shfl_xor(lsum, 32);
  const float linv = 1.0f / lt;
  bf16* Orow = Og + ((size_t)b * SEQ + q0 + q) * E_DIM + h * HD;
#pragma unroll
  for (int db = 0; db < 4; db++)
#pragma unroll
    for (int g4 = 0; g4 < 4; g4++) {
      bf16x4 ov;
#pragma unroll
      for (int i = 0; i < 4; i++) ov[i] = (bf16)(o[db][g4 * 4 + i] * linv);
      *(bf16x4*)(Orow + db * 32 + g4 * 8 + hi * 4) = ov;
    }
}

// ---------------- fused thought cross-attn + LayerNorm ----------------
__global__ __launch_bounds__(256) void thought_ln_kernel(
    const bf16* __restrict__ TQ, const float* __restrict__ TK,
    const float* __restrict__ TV, const bf16* __restrict__ ATT,
    const float* __restrict__ gamma, const float* __restrict__ beta,
    bf16* __restrict__ Y)
{
  __shared__ float wsum[4], wsq[4];
  const int tid = threadIdx.x;
  const int lane = tid & 63;
  const int w = tid >> 6;
  const int tok = blockIdx.x;            // b*SEQ + s
  const int b = tok >> 11, s = tok & 2047;
  const int e0 = tid * 8;
  const int h = e0 >> 7;
  const int d0 = e0 & 127;

  const bf16x8 av = *(const bf16x8*)(ATT + (size_t)tok * E_DIM + e0);
  float v[8];
#pragma unroll
  for (int i = 0; i < 8; i++) v[i] = (float)av[i];

  const bf16x8 qv8 = *(const bf16x8*)(TQ + (((size_t)(b * HEADS + h)) * SEQ + s) * HD + d0);
  float qv[8];
#pragma unroll
  for (int i = 0; i < 8; i++) qv[i] = (float)qv8[i];

  float dts[NSLOT];
#pragma unroll
  for (int sl = 0; sl < NSLOT; sl++) {
    const float* tkr = TK + (size_t)sl * E_DIM + e0;
    const f32x4 k0 = *(const f32x4*)(tkr);
    const f32x4 k1 = *(const f32x4*)(tkr + 4);
    float dp = 0.f;
#pragma unroll
    for (int i = 0; i < 4; i++) dp += qv[i] * k0[i] + qv[4 + i] * k1[i];
    dp += __shfl_xor(dp, 1);
    dp += __shfl_xor(dp, 2);
    dp += __shfl_xor(dp, 4);
    dp += __shfl_xor(dp, 8);
    dts[sl] = dp;
  }
  float mx = dts[0];
#pragma unroll
  for (int sl = 1; sl < NSLOT; sl++) mx = fmaxf(mx, dts[sl]);
  float p[NSLOT], den = 0.f;
#pragma unroll
  for (int sl = 0; sl < NSLOT; sl++) { p[sl] = exp2f(dts[sl] - mx); den += p[sl]; }
  const float dinv = 1.0f / den;
#pragma unroll
  for (int sl = 0; sl < NSLOT; sl++) {
    const float pn = p[sl] * dinv;
    const float* tvr = TV + (size_t)sl * E_DIM + e0;
    const f32x4 v0 = *(const f32x4*)(tvr);
    const f32x4 v1 = *(const f32x4*)(tvr + 4);
#pragma unroll
    for (int i = 0; i < 4; i++) { v[i] += pn * v0[i]; v[4 + i] += pn * v1[i]; }
  }

  float sm = 0.f, sq = 0.f;
#pragma unroll
  for (int i = 0; i < 8; i++) { sm += v[i]; sq += v[i] * v[i]; }
#pragma unroll
  for (int d = 1; d < 64; d <<= 1) { sm += __shfl_xor(sm, d); sq += __shfl_xor(sq, d); }
  if (lane == 0) { wsum[w] = sm; wsq[w] = sq; }
  __syncthreads();
  const float ts = wsum[0] + wsum[1] + wsum[2] + wsum[3];
  const float tq2 = wsq[0] + wsq[1] + wsq[2] + wsq[3];
  const float mean = ts * (1.f / E_DIM);
  const float var = tq2 * (1.f / E_DIM) - mean * mean;
  const float rstd = rsqrtf(var + 1e-5f);
  const f32x4 g0 = *(const f32x4*)(gamma + e0);
  const f32x4 g1 = *(const f32x4*)(gamma + e0 + 4);
  const f32x4 b0 = *(const f32x4*)(beta + e0);
  const f32x4 b1 = *(const f32x4*)(beta + e0 + 4);
  bf16x8 outv;
#pragma unroll
  for (int i = 0; i < 4; i++) {
    outv[i]     = (bf16)((v[i]     - mean) * rstd * g0[i] + b0[i]);
    outv[4 + i] = (bf16)((v[4 + i] - mean) * rstd * g1[i] + b1[i]);
  }
  *(bf16x8*)(Y + (size_t)tok * E_DIM + e0) = outv;
}

extern "C" void kernel_launch(void* const* d_in, const int* in_sizes, int n_in,
                              void* d_out, int out_size, void* d_ws, size_t ws_size,
                              hipStream_t stream) {
  (void)in_sizes; (void)n_in; (void)out_size; (void)ws_size;
  const float* x     = (const float*)d_in[0];
  const float* slots = (const float*)d_in[1];
  const float* Wq  = (const float*)d_in[2];   const float* bq  = (const float*)d_in[3];
  const float* Wk  = (const float*)d_in[4];   const float* bk  = (const float*)d_in[5];
  const float* Wv  = (const float*)d_in[6];   const float* bv  = (const float*)d_in[7];
  const float* Wtq = (const float*)d_in[8];   const float* btq = (const float*)d_in[9];
  const float* Wtk = (const float*)d_in[10];  const float* btk = (const float*)d_in[11];
  const float* Wtv = (const float*)d_in[12];  const float* btv = (const float*)d_in[13];
  const float* Wo  = (const float*)d_in[14];  const float* bo  = (const float*)d_in[15];
  const float* gamma = (const float*)d_in[16];
  const float* beta  = (const float*)d_in[17];

  uint8_t* ws = (uint8_t*)d_ws;
  const size_t BUF  = (size_t)NTOK * E_DIM * sizeof(bf16);    // 16 MiB (activations)
  const size_t WBUF = (size_t)E_DIM * E_DIM * sizeof(bf16);   // 8 MiB (weights)
  bf16* xb   = (bf16*)(ws + 0 * BUF);          // [B,S,E] bf16 x
  bf16* qb   = (bf16*)(ws + 1 * BUF);          // [B,H,S,D] (pre-scaled)
  bf16* kb   = (bf16*)(ws + 2 * BUF);          // [B,H,S,D]
  bf16* vtb  = (bf16*)(ws + 3 * BUF);          // [B,H,D,S]
  bf16* tqb  = (bf16*)(ws + 4 * BUF);          // [B,H,S,D] (pre-scaled)
  bf16* attb = (bf16*)(ws + 5 * BUF);          // [B,S,E] flash output
  bf16* nrmb = qb;                             // alias: qb dead after flash
  uint8_t* wp = ws + 6 * BUF;
  bf16* Wqb  = (bf16*)(wp + 0 * WBUF);
  bf16* Wkb  = (bf16*)(wp + 1 * WBUF);
  bf16* Wvb  = (bf16*)(wp + 2 * WBUF);
  bf16* Wtqb = (bf16*)(wp + 3 * WBUF);
  bf16* Wob  = (bf16*)(wp + 4 * WBUF);
  float* tkb = (float*)(wp + 5 * WBUF);               // [8][E] f32
  float* tvb = (float*)(wp + 5 * WBUF + 128 * 1024);  // [8][E] f32

  // --- convert f32 -> bf16 for MFMA consumers ---
  const int WN8 = E_DIM * E_DIM / 8;   // 524288
  const int XN8 = NTOK * E_DIM / 8;    // 1048576
  cvt_f32_bf16_kernel<<<dim3(2048), 256, 0, stream>>>(x, xb, XN8);
  cvt_f32_bf16_kernel<<<dim3(1024), 256, 0, stream>>>(Wq, Wqb, WN8);
  cvt_f32_bf16_kernel<<<dim3(1024), 256, 0, stream>>>(Wk, Wkb, WN8);
  cvt_f32_bf16_kernel<<<dim3(1024), 256, 0, stream>>>(Wv, Wvb, WN8);
  cvt_f32_bf16_kernel<<<dim3(1024), 256, 0, stream>>>(Wtq, Wtqb, WN8);
  cvt_f32_bf16_kernel<<<dim3(1024), 256, 0, stream>>>(Wo, Wob, WN8);

  // --- projections (Q and TQ pre-scaled by 1/sqrt(D)*log2e) ---
  ProjArgs pa;
  pa.W[0] = Wqb;  pa.bias[0] = bq;  pa.out[0] = qb;  pa.mode[0] = 1; pa.scale[0] = QSCALE;
  pa.W[1] = Wkb;  pa.bias[1] = bk;  pa.out[1] = kb;  pa.mode[1] = 1; pa.scale[1] = 1.0f;
  pa.W[2] = Wvb;  pa.bias[2] = bv;  pa.out[2] = vtb; pa.mode[2] = 2; pa.scale[2] = 1.0f;
  pa.W[3] = Wtqb; pa.bias[3] = btq; pa.out[3] = tqb; pa.mode[3] = 1; pa.scale[3] = QSCALE;
  gemm256_kernel<<<dim3(16 * 8 * 4), 512, 0, stream>>>(xb, pa, 16, 8);

  slots_proj_kernel<<<dim3(E_DIM / 256, NSLOT, 2), 256, 0, stream>>>(
      slots, Wtk, btk, Wtv, btv, tkb, tvb);

  // --- attention streams ---
  flash_attn_kernel<<<dim3((SEQ / 256) * BATCH * HEADS), 512, 0, stream>>>(
      qb, kb, vtb, attb);
  thought_ln_kernel<<<dim3(NTOK), 256, 0, stream>>>(
      tqb, tkb, tvb, attb, gamma, beta, nrmb);

  // --- output projection (f32 out), 128^2 tiles: 512 blocks = 2/CU ---
  ProjArgs po;
  po.W[0] = Wob; po.bias[0] = bo; po.out[0] = d_out; po.mode[0] = 0; po.scale[0] = 1.0f;
  po.W[1] = po.W[2] = po.W[3] = Wob;
  po.bias[1] = po.bias[2] = po.bias[3] = bo;
  po.out[1] = po.out[2] = po.out[3] = d_out;
  po.mode[1] = po.mode[2] = po.mode[3] = 0;
  po.scale[1] = po.scale[2] = po.scale[3] = 1.0f;
  gemm_nt_kernel<<<dim3(NTOK / 128, E_DIM / 128, 1), 256, 0, stream>>>(
      nrmb, po, NTOK, E_DIM, E_DIM);
}

// Round 11
// 448.664 us; speedup vs baseline: 1.2243x; 1.0389x over previous
//
#include <hip/hip_runtime.h>
#include <hip/hip_bf16.h>
#include <stdint.h>

typedef __bf16 bf16;
typedef __bf16 bf16x8 __attribute__((ext_vector_type(8)));
typedef __bf16 bf16x4 __attribute__((ext_vector_type(4)));
typedef float f32x4 __attribute__((ext_vector_type(4)));
typedef float f32x16 __attribute__((ext_vector_type(16)));
typedef uint32_t u32x2 __attribute__((ext_vector_type(2)));
typedef uint32_t u32x4 __attribute__((ext_vector_type(4)));

#define E_DIM 2048
#define HEADS 16
#define HD 128
#define SEQ 2048
#define BATCH 2
#define NTOK 4096
#define NSLOT 8

// 1/sqrt(128) * log2(e): folded into Q / TQ at projection time
#define QSCALE (0.08838834764831845f * 1.4426950408889634f)

#define WAITV(N) asm volatile("s_waitcnt vmcnt(" #N ")" ::: "memory")

__device__ __forceinline__ void gload_lds16(const void* g, void* lds) {
  __builtin_amdgcn_global_load_lds(
      (const __attribute__((address_space(1))) uint32_t*)g,
      (__attribute__((address_space(3))) uint32_t*)lds, 16, 0, 0);
}

// ---------------- f32 -> bf16 convert ----------------
__global__ __launch_bounds__(256) void cvt_f32_bf16_kernel(
    const float* __restrict__ src, bf16* __restrict__ dst, int n8)
{
  for (int i = blockIdx.x * 256 + threadIdx.x; i < n8; i += gridDim.x * 256) {
    const f32x4 a = *(const f32x4*)(src + i * 8);
    const f32x4 b = *(const f32x4*)(src + i * 8 + 4);
    bf16x8 o;
#pragma unroll
    for (int j = 0; j < 4; j++) { o[j] = (bf16)a[j]; o[4 + j] = (bf16)b[j]; }
    *(bf16x8*)(dst + i * 8) = o;
  }
}

struct CvtArgs { const float* src[5]; bf16* dst[5]; };

// batched weight convert: blockIdx.y selects tensor (all same size)
__global__ __launch_bounds__(256) void cvt5_kernel(CvtArgs a, int n8)
{
  const float* __restrict__ src = a.src[blockIdx.y];
  bf16* __restrict__ dst = a.dst[blockIdx.y];
  for (int i = blockIdx.x * 256 + threadIdx.x; i < n8; i += gridDim.x * 256) {
    const f32x4 x = *(const f32x4*)(src + i * 8);
    const f32x4 y = *(const f32x4*)(src + i * 8 + 4);
    bf16x8 o;
#pragma unroll
    for (int j = 0; j < 4; j++) { o[j] = (bf16)x[j]; o[4 + j] = (bf16)y[j]; }
    *(bf16x8*)(dst + i * 8) = o;
  }
}

struct ProjArgs {
  const bf16* W[4];
  const float* bias[4];
  void* out[4];
  int mode[4];     // 0: f32 row-major [M][N=2048]; 1: bf16 [B,H,S,D]; 2: bf16 [B,H,D,S]
  float scale[4];  // applied AFTER bias
};

// ---------------- 256x256 NT GEMM, 4-phase/K-tile, counted vmcnt(6), reg-held B -----
// (round-10 measured-best: 192 us for 4 fused GEMMs, 0 bank conflicts)
__global__ __launch_bounds__(512, 2) void gemm256_kernel(
    const bf16* __restrict__ A, ProjArgs pa, int nbm, int nbn)
{
  __shared__ char As_[2 * 32768];
  __shared__ char Bs_[2 * 32768];

  const int nwg = gridDim.x;
  const int qch = nwg >> 3;
  const int wg = (blockIdx.x & 7) * qch + (blockIdx.x >> 3);
  const int bm = wg % nbm;
  const int rest = wg / nbm;
  const int bn = rest % nbn;
  const int z = rest / nbn;

  const bf16* __restrict__ W = pa.W[z];
  const float* __restrict__ bias = pa.bias[z];
  void* __restrict__ out = pa.out[z];
  const int mode = pa.mode[z];
  const float scale = pa.scale[z];

  const int tid = threadIdx.x;
  const int lane = tid & 63;
  const int w = tid >> 6;          // 0..7
  const int wr = w >> 2;           // 0..1 (M)
  const int wc = w & 3;            // 0..3 (N)
  const int g = lane >> 4, c = lane & 15;

  const int srow = tid >> 3;                       // 0..63
  const int sslot = tid & 7;
  const int scol = (sslot ^ (srow & 7)) * 8;
  const bf16* Abase = A + (size_t)(bm * 256) * 2048;
  const bf16* Bbase = W + (size_t)(bn * 256) * 2048;

  auto stageU = [&](const bf16* gbase, char* lds, int T, int u) {
    char* dst = lds + (T & 1) * 32768 + u * 16384;
    const int k0 = T * 64;
#pragma unroll
    for (int j = 0; j < 2; j++) {
      const int r = u * 128 + srow + j * 64;
      gload_lds16(gbase + (size_t)r * 2048 + k0 + scol,
                  dst + (size_t)(srow + j * 64) * 128 + sslot * 16);
    }
  };

  f32x4 acc[8][4] = {};
  bf16x8 bfr[4][2];                // B fragments, held across the 4 phases

  stageU(Bbase, Bs_, 0, 0); stageU(Bbase, Bs_, 0, 1);
  stageU(Abase, As_, 0, 0); stageU(Abase, As_, 0, 1);
  stageU(Bbase, Bs_, 1, 0); stageU(Bbase, Bs_, 1, 1);
  stageU(Abase, As_, 1, 0);
  WAITV(6);
  __builtin_amdgcn_s_barrier();

  const int NT = 2048 / 64;        // 32
  for (int t = 0; t < NT; t++) {
    const int d = t & 1;
    const char* Aq = As_ + d * 32768;
    const char* Bq = Bs_ + d * 32768;
#pragma unroll
    for (int q = 0; q < 4; q++) {
      bf16x8 af[2][2];
      if (q == 0) {
#pragma unroll
        for (int n = 0; n < 4; n++)
#pragma unroll
          for (int kk = 0; kk < 2; kk++) {
            const int row = wc * 64 + n * 16 + c;
            bfr[n][kk] = *(const bf16x8*)(Bq + (size_t)row * 128 +
                                          (((kk * 4 + g) ^ (c & 7)) * 16));
          }
      }
#pragma unroll
      for (int mi2 = 0; mi2 < 2; mi2++)
#pragma unroll
        for (int kk = 0; kk < 2; kk++) {
          const int row = wr * 128 + (q * 2 + mi2) * 16 + c;
          af[mi2][kk] = *(const bf16x8*)(Aq + (size_t)row * 128 +
                                         (((kk * 4 + g) ^ (c & 7)) * 16));
        }

      __builtin_amdgcn_s_barrier();

      if (q == 0)      { if (t + 1 < NT) stageU(Abase, As_, t + 1, 1); }
      else if (q == 1) { if (t + 2 < NT) stageU(Bbase, Bs_, t + 2, 0); }
      else if (q == 2) { if (t + 2 < NT) stageU(Bbase, Bs_, t + 2, 1); }
      else             { if (t + 2 < NT) stageU(Abase, As_, t + 2, 0); }

      __builtin_amdgcn_s_setprio(1);
#pragma unroll
      for (int mi2 = 0; mi2 < 2; mi2++)
#pragma unroll
        for (int n = 0; n < 4; n++)
#pragma unroll
          for (int kk = 0; kk < 2; kk++)
            acc[q * 2 + mi2][n] = __builtin_amdgcn_mfma_f32_16x16x32_bf16(
                af[mi2][kk], bfr[n][kk], acc[q * 2 + mi2][n], 0, 0, 0);
      __builtin_amdgcn_s_setprio(0);

      if (q == 3) {
        if (t < NT - 2)       { WAITV(6); }
        else if (t == NT - 2) { WAITV(0); }
      }
      __builtin_amdgcn_s_barrier();
    }
  }

#pragma unroll
  for (int mi = 0; mi < 8; mi++) {
#pragma unroll
    for (int n = 0; n < 4; n++) {
      const int col = bn * 256 + wc * 64 + n * 16 + c;
      const float bv = bias[col];
#pragma unroll
      for (int j = 0; j < 4; j++) {
        const int row = bm * 256 + wr * 128 + mi * 16 + g * 4 + j;
        const float v = (acc[mi][n][j] + bv) * scale;
        if (mode == 0) {
          ((float*)out)[(size_t)row * E_DIM + col] = v;
        } else {
          const int b = row >> 11, s = row & 2047;
          const int h = col >> 7, d2 = col & 127;
          size_t idx;
          if (mode == 1) idx = (((size_t)(b * HEADS + h)) * SEQ + s) * HD + d2;
          else           idx = (((size_t)(b * HEADS + h)) * HD + d2) * SEQ + s;
          ((bf16*)out)[idx] = (bf16)v;
        }
      }
    }
  }
}

// ---------------- 128x128 NT GEMM (final projection) ----------
__global__ __launch_bounds__(256) void gemm_nt_kernel(
    const bf16* __restrict__ A, ProjArgs pa, int M, int N, int K)
{
  __shared__ bf16 As[2][128 * 32];
  __shared__ bf16 Bs[2][128 * 32];

  const int z = blockIdx.z;
  const bf16* __restrict__ W = pa.W[z];
  const float* __restrict__ bias = pa.bias[z];
  void* __restrict__ out = pa.out[z];
  const int mode = pa.mode[z];
  const float scale = pa.scale[z];

  const int tid = threadIdx.x;
  const int lane = tid & 63;
  const int w = tid >> 6;
  const int wr = w >> 1, wc = w & 1;
  const int g = lane >> 4, c = lane & 15;
  const int bm = blockIdx.x, bn = blockIdx.y;

  f32x4 acc[4][4] = {};

  const int srow = lane >> 2;          // 0..15
  const int scol = (lane & 3) * 8;     // 0,8,16,24
  const bf16* Ab = A + (size_t)(bm * 128 + srow) * K + scol;
  const bf16* Wb = W + (size_t)(bn * 128 + srow) * K + scol;

  auto stage = [&](int k0, int buf) {
#pragma unroll
    for (int i = 0; i < 2; ++i) {
      const int chunk = w * 2 + i;
      gload_lds16(Ab + (size_t)(chunk * 16) * K + k0, (char*)(&As[buf][0]) + chunk * 1024);
      gload_lds16(Wb + (size_t)(chunk * 16) * K + k0, (char*)(&Bs[buf][0]) + chunk * 1024);
    }
  };

  stage(0, 0);
  __syncthreads();
  int cur = 0;

  for (int k0 = 0; k0 < K; k0 += 32) {
    if (k0 + 32 < K) stage(k0 + 32, cur ^ 1);
    bf16x8 af[4], bfr[4];
#pragma unroll
    for (int m = 0; m < 4; m++)
      af[m] = *(const bf16x8*)(&As[cur][0] + (wr * 64 + m * 16 + c) * 32 + g * 8);
#pragma unroll
    for (int n = 0; n < 4; n++)
      bfr[n] = *(const bf16x8*)(&Bs[cur][0] + (wc * 64 + n * 16 + c) * 32 + g * 8);
#pragma unroll
    for (int m = 0; m < 4; m++)
#pragma unroll
      for (int n = 0; n < 4; n++)
        acc[m][n] = __builtin_amdgcn_mfma_f32_16x16x32_bf16(af[m], bfr[n], acc[m][n], 0, 0, 0);
    __syncthreads();
    cur ^= 1;
  }

#pragma unroll
  for (int m = 0; m < 4; m++) {
#pragma unroll
    for (int n = 0; n < 4; n++) {
      const int col = bn * 128 + wc * 64 + n * 16 + c;
      const float bv = bias[col];
#pragma unroll
      for (int j = 0; j < 4; j++) {
        const int row = bm * 128 + wr * 64 + m * 16 + g * 4 + j;
        const float v = (acc[m][n][j] + bv) * scale;
        if (mode == 0) {
          ((float*)out)[(size_t)row * N + col] = v;
        } else {
          const int b = row >> 11, s = row & 2047;
          const int h = col >> 7, d = col & 127;
          size_t idx;
          if (mode == 1) idx = (((size_t)(b * HEADS + h)) * SEQ + s) * HD + d;
          else           idx = (((size_t)(b * HEADS + h)) * HD + d) * SEQ + s;
          ((bf16*)out)[idx] = (bf16)v;
        }
      }
    }
  }
}

// ---------------- slots projections ----------------
__global__ __launch_bounds__(256) void slots_proj_kernel(
    const float* __restrict__ slots,
    const float* __restrict__ Wk, const float* __restrict__ bk,
    const float* __restrict__ Wv, const float* __restrict__ bv,
    float* __restrict__ tk, float* __restrict__ tv)
{
  const int col = blockIdx.x * 256 + threadIdx.x;
  const int slot = blockIdx.y;
  const int mat = blockIdx.z;
  const float* W = mat ? Wv : Wk;
  const float* bias = mat ? bv : bk;
  float* out = mat ? tv : tk;
  const float* xr = slots + (size_t)slot * E_DIM;
  const float* wr = W + (size_t)col * E_DIM;
  float acc = 0.f;
  for (int k = 0; k < E_DIM; k += 4) {
    const f32x4 a = *(const f32x4*)(xr + k);
    const f32x4 b4 = *(const f32x4*)(wr + k);
#pragma unroll
    for (int i = 0; i < 4; i++) acc += a[i] * b4[i];
  }
  out[(size_t)slot * E_DIM + col] = acc + bias[col];
}

// ---------------- flash attention: 8-wave 32x32, T15 deferred-PV pipeline ----------------
// Q pre-scaled. Per iteration t: stage(t+1) -> buf[(t+1)%3] (slab t-2 dead since
// iter t-1's barrier); QK^T(t) [MFMA]; softmax-core(t) [VALU] and PV(t-1) [MFMA]
// mutually independent -> co-scheduled; o-rescale AFTER PV(t-1) (exact algebra:
// o enters iter t at scale m(t-1) missing P(t-1)V(t-1)); single __syncthreads
// per iter drains own staging. Epilogue adds PV(NT-1).
__global__ __launch_bounds__(512) void flash_attn_kernel(
    const bf16* __restrict__ Qg, const bf16* __restrict__ Kg,
    const bf16* __restrict__ Vtg, bf16* __restrict__ Og)
{
  __shared__ char Ks[3][64 * 256];    // [kv][d] bf16, 256B rows, slot ^= r&15
  __shared__ char Vs[3][128 * 128];   // [d][kv] bf16, 128B rows, slot ^= r&7

  const int orig = blockIdx.x;                 // 256 blocks
  const int logical = (orig & 7) * 32 + (orig >> 3);   // XCD swizzle
  const int qt = logical & 7;
  const int bh = logical >> 3;

  const int tid = threadIdx.x;
  const int lane = tid & 63;
  const int w = tid >> 6;          // 0..7
  const int q = lane & 31;
  const int hi = lane >> 5;
  const int b = bh >> 4, h = bh & 15;
  const int q0 = qt * 256 + w * 32;

  const bf16* Qb = Qg + ((size_t)bh * SEQ + q0) * HD;
  const bf16* Kb = Kg + (size_t)bh * SEQ * HD;
  const bf16* Vb = Vtg + (size_t)bh * HD * SEQ;

  auto stage = [&](int kv0, int buf) {
#pragma unroll
    for (int i = 0; i < 2; i++) {
      const int p = (tid + i * 512) * 16;
      { const int r = p >> 8; const int s16 = (p >> 4) & 15;
        gload_lds16(Kb + (size_t)(kv0 + r) * HD + (s16 ^ (r & 15)) * 8, &Ks[0][0] + buf * 16384 + p); }
      { const int r = p >> 7; const int s8 = (p >> 4) & 7;
        gload_lds16(Vb + (size_t)r * SEQ + kv0 + (s8 ^ (r & 7)) * 8, &Vs[0][0] + buf * 16384 + p); }
    }
  };

  // Q B-operand fragments: qf[kc][j] = Q[q][kc*16 + 8*hi + j]
  bf16x8 qf[8];
#pragma unroll
  for (int kc = 0; kc < 8; kc++)
    qf[kc] = *(const bf16x8*)(Qb + (size_t)q * HD + kc * 16 + hi * 8);

  f32x16 o[4] = {};                  // O^T[d][q]
  float mrun = -1e30f, lsum = 0.f;
  bf16x8 pbo[2][2];                  // previous tile's P fragments (PV deferred)

  stage(0, 0);
  __syncthreads();

  int prv = 2, cur = 0, nxt = 1;     // rotating buffer indices
  const int NT = SEQ / 64;           // 32

  for (int t = 0; t < NT; t++) {
    if (t + 1 < NT) stage((t + 1) * 64, nxt);

    // S^T[kv][q] = K(t) . Q^T
    f32x16 st[2] = {};
    const char* Kc = &Ks[0][0] + cur * 16384;
    __builtin_amdgcn_s_setprio(1);
#pragma unroll
    for (int kc = 0; kc < 8; kc++) {
#pragma unroll
      for (int blk = 0; blk < 2; blk++) {
        const int rt = blk * 32 + q;
        const int sl = (2 * kc + hi) ^ (rt & 15);
        const bf16x8 kf = *(const bf16x8*)(Kc + rt * 256 + sl * 16);
        st[blk] = __builtin_amdgcn_mfma_f32_32x32x16_bf16(kf, qf[kc], st[blk], 0, 0, 0);
      }
    }
    __builtin_amdgcn_s_setprio(0);

    // max + defer-max decision
    float tm[16];
#pragma unroll
    for (int i = 0; i < 16; i++) tm[i] = fmaxf(st[0][i], st[1][i]);
#pragma unroll
    for (int s2 = 8; s2 > 0; s2 >>= 1)
#pragma unroll
      for (int i = 0; i < 8; i++) if (i < s2) tm[i] = fmaxf(tm[i], tm[i + s2]);
    float lm = tm[0];
    lm = fmaxf(lm, __shfl_xor(lm, 32));
    float fsc = 1.0f;
    const bool resc = __any(lm > mrun + 8.0f);
    if (resc) {
      const float mn = fmaxf(mrun, lm);
      fsc = exp2f(mrun - mn);
      mrun = mn;
    }

    // --- independent region: softmax-core(t) [VALU/TRANS] + PV(t-1) [MFMA] ---
    float ps0 = 0.f, ps1 = 0.f, ps2 = 0.f, ps3 = 0.f;
#pragma unroll
    for (int blk = 0; blk < 2; blk++)
#pragma unroll
      for (int i = 0; i < 16; i += 4) {
        const float p0 = exp2f(st[blk][i]     - mrun);
        const float p1 = exp2f(st[blk][i + 1] - mrun);
        const float p2 = exp2f(st[blk][i + 2] - mrun);
        const float p3 = exp2f(st[blk][i + 3] - mrun);
        st[blk][i] = p0; st[blk][i + 1] = p1; st[blk][i + 2] = p2; st[blk][i + 3] = p3;
        ps0 += p0; ps1 += p1; ps2 += p2; ps3 += p3;
      }
    lsum = lsum * fsc + ((ps0 + ps1) + (ps2 + ps3));

    bf16x8 pbn[2][2];
#pragma unroll
    for (int blk = 0; blk < 2; blk++)
#pragma unroll
      for (int c2 = 0; c2 < 2; c2++) {
        bf16x4 Lv, Hv;
#pragma unroll
        for (int i = 0; i < 4; i++) {
          Lv[i] = (bf16)st[blk][8 * c2 + i];
          Hv[i] = (bf16)st[blk][8 * c2 + 4 + i];
        }
        const u32x2 Lu = __builtin_bit_cast(u32x2, Lv);
        const u32x2 Hu = __builtin_bit_cast(u32x2, Hv);
        const uint32_t s0 = hi ? Lu.x : Hu.x;
        const uint32_t s1 = hi ? Lu.y : Hu.y;
        const uint32_t x0 = (uint32_t)__shfl_xor((int)s0, 32);
        const uint32_t x1 = (uint32_t)__shfl_xor((int)s1, 32);
        u32x4 bv;
        bv.x = hi ? x0 : Lu.x;
        bv.y = hi ? x1 : Lu.y;
        bv.z = hi ? Hu.x : x0;
        bv.w = hi ? Hu.y : x1;
        pbn[blk][c2] = __builtin_bit_cast(bf16x8, bv);
      }

    if (t > 0) {   // PV(t-1): o += V(t-1)^T . P(t-1)^T   (independent of above)
      const char* Vc = &Vs[0][0] + prv * 16384;
#pragma unroll
      for (int db = 0; db < 4; db++) {
        const int rt = db * 32 + q;
#pragma unroll
        for (int blk = 0; blk < 2; blk++)
#pragma unroll
          for (int c2 = 0; c2 < 2; c2++) {
            const int sl = (blk * 4 + c2 * 2 + hi) ^ (rt & 7);
            const bf16x8 vf = *(const bf16x8*)(Vc + rt * 128 + sl * 16);
            o[db] = __builtin_amdgcn_mfma_f32_32x32x16_bf16(vf, pbn ? pbo[blk][c2] : pbo[blk][c2], o[db], 0, 0, 0);
          }
      }
    }

    // rescale AFTER PV(t-1): o now complete through t-1 at scale m(t-1)
    if (resc) {
#pragma unroll
      for (int db = 0; db < 4; db++)
#pragma unroll
        for (int i = 0; i < 16; i++) o[db][i] *= fsc;
    }

#pragma unroll
    for (int blk = 0; blk < 2; blk++)
#pragma unroll
      for (int c2 = 0; c2 < 2; c2++) pbo[blk][c2] = pbn[blk][c2];

    __syncthreads();   // drains own staging vmcnt; all waves' reads of prv/cur done
    const int tmp = prv; prv = cur; cur = nxt; nxt = tmp;
  }

  // epilogue: PV(NT-1) from buf prv (= (NT-1)%3 after final rotation)
  {
    const char* Vc = &Vs[0][0] + prv * 16384;
#pragma unroll
    for (int db = 0; db < 4; db++) {
      const int rt = db * 32 + q;
#pragma unroll
      for (int blk = 0; blk < 2; blk++)
#pragma unroll
        for (int c2 = 0; c2 < 2; c2++) {
          const int sl = (blk * 4 + c2 * 2 + hi) ^ (rt & 7);
          const bf16x8 vf = *(const bf16x8*)(Vc + rt * 128 + sl * 16);
          o[db] = __builtin_amdgcn_mfma_f32_32x32x16_bf16(vf, pbo[blk][c2], o[db], 0, 0, 0);
        }
    }
  }

  // normalize + store
  const float lt = lsum + __shfl_xor(lsum, 32);
  const float linv = 1.0f / lt;
  bf16* Orow = Og + ((size_t)b * SEQ + q0 + q) * E_DIM + h * HD;
#pragma unroll
  for (int db = 0; db < 4; db++)
#pragma unroll
    for (int g4 = 0; g4 < 4; g4++) {
      bf16x4 ov;
#pragma unroll
      for (int i = 0; i < 4; i++) ov[i] = (bf16)(o[db][g4 * 4 + i] * linv);
      *(bf16x4*)(Orow + db * 32 + g4 * 8 + hi * 4) = ov;
    }
}

// ---------------- fused thought cross-attn + LayerNorm ----------------
__global__ __launch_bounds__(256) void thought_ln_kernel(
    const bf16* __restrict__ TQ, const float* __restrict__ TK,
    const float* __restrict__ TV, const bf16* __restrict__ ATT,
    const float* __restrict__ gamma, const float* __restrict__ beta,
    bf16* __restrict__ Y)
{
  __shared__ float wsum[4], wsq[4];
  const int tid = threadIdx.x;
  const int lane = tid & 63;
  const int w = tid >> 6;
  const int tok = blockIdx.x;            // b*SEQ + s
  const int b = tok >> 11, s = tok & 2047;
  const int e0 = tid * 8;
  const int h = e0 >> 7;
  const int d0 = e0 & 127;

  const bf16x8 av = *(const bf16x8*)(ATT + (size_t)tok * E_DIM + e0);
  float v[8];
#pragma unroll
  for (int i = 0; i < 8; i++) v[i] = (float)av[i];

  const bf16x8 qv8 = *(const bf16x8*)(TQ + (((size_t)(b * HEADS + h)) * SEQ + s) * HD + d0);
  float qv[8];
#pragma unroll
  for (int i = 0; i < 8; i++) qv[i] = (float)qv8[i];

  float dts[NSLOT];
#pragma unroll
  for (int sl = 0; sl < NSLOT; sl++) {
    const float* tkr = TK + (size_t)sl * E_DIM + e0;
    const f32x4 k0 = *(const f32x4*)(tkr);
    const f32x4 k1 = *(const f32x4*)(tkr + 4);
    float dp = 0.f;
#pragma unroll
    for (int i = 0; i < 4; i++) dp += qv[i] * k0[i] + qv[4 + i] * k1[i];
    dp += __shfl_xor(dp, 1);
    dp += __shfl_xor(dp, 2);
    dp += __shfl_xor(dp, 4);
    dp += __shfl_xor(dp, 8);
    dts[sl] = dp;
  }
  float mx = dts[0];
#pragma unroll
  for (int sl = 1; sl < NSLOT; sl++) mx = fmaxf(mx, dts[sl]);
  float p[NSLOT], den = 0.f;
#pragma unroll
  for (int sl = 0; sl < NSLOT; sl++) { p[sl] = exp2f(dts[sl] - mx); den += p[sl]; }
  const float dinv = 1.0f / den;
#pragma unroll
  for (int sl = 0; sl < NSLOT; sl++) {
    const float pn = p[sl] * dinv;
    const float* tvr = TV + (size_t)sl * E_DIM + e0;
    const f32x4 v0 = *(const f32x4*)(tvr);
    const f32x4 v1 = *(const f32x4*)(tvr + 4);
#pragma unroll
    for (int i = 0; i < 4; i++) { v[i] += pn * v0[i]; v[4 + i] += pn * v1[i]; }
  }

  float sm = 0.f, sq = 0.f;
#pragma unroll
  for (int i = 0; i < 8; i++) { sm += v[i]; sq += v[i] * v[i]; }
#pragma unroll
  for (int d = 1; d < 64; d <<= 1) { sm += __shfl_xor(sm, d); sq += __shfl_xor(sq, d); }
  if (lane == 0) { wsum[w] = sm; wsq[w] = sq; }
  __syncthreads();
  const float ts = wsum[0] + wsum[1] + wsum[2] + wsum[3];
  const float tq2 = wsq[0] + wsq[1] + wsq[2] + wsq[3];
  const float mean = ts * (1.f / E_DIM);
  const float var = tq2 * (1.f / E_DIM) - mean * mean;
  const float rstd = rsqrtf(var + 1e-5f);
  const f32x4 g0 = *(const f32x4*)(gamma + e0);
  const f32x4 g1 = *(const f32x4*)(gamma + e0 + 4);
  const f32x4 b0 = *(const f32x4*)(beta + e0);
  const f32x4 b1 = *(const f32x4*)(beta + e0 + 4);
  bf16x8 outv;
#pragma unroll
  for (int i = 0; i < 4; i++) {
    outv[i]     = (bf16)((v[i]     - mean) * rstd * g0[i] + b0[i]);
    outv[4 + i] = (bf16)((v[4 + i] - mean) * rstd * g1[i] + b1[i]);
  }
  *(bf16x8*)(Y + (size_t)tok * E_DIM + e0) = outv;
}

extern "C" void kernel_launch(void* const* d_in, const int* in_sizes, int n_in,
                              void* d_out, int out_size, void* d_ws, size_t ws_size,
                              hipStream_t stream) {
  (void)in_sizes; (void)n_in; (void)out_size; (void)ws_size;
  const float* x     = (const float*)d_in[0];
  const float* slots = (const float*)d_in[1];
  const float* Wq  = (const float*)d_in[2];   const float* bq  = (const float*)d_in[3];
  const float* Wk  = (const float*)d_in[4];   const float* bk  = (const float*)d_in[5];
  const float* Wv  = (const float*)d_in[6];   const float* bv  = (const float*)d_in[7];
  const float* Wtq = (const float*)d_in[8];   const float* btq = (const float*)d_in[9];
  const float* Wtk = (const float*)d_in[10];  const float* btk = (const float*)d_in[11];
  const float* Wtv = (const float*)d_in[12];  const float* btv = (const float*)d_in[13];
  const float* Wo  = (const float*)d_in[14];  const float* bo  = (const float*)d_in[15];
  const float* gamma = (const float*)d_in[16];
  const float* beta  = (const float*)d_in[17];

  uint8_t* ws = (uint8_t*)d_ws;
  const size_t BUF  = (size_t)NTOK * E_DIM * sizeof(bf16);    // 16 MiB
  const size_t WBUF = (size_t)E_DIM * E_DIM * sizeof(bf16);   // 8 MiB
  bf16* xb   = (bf16*)(ws + 0 * BUF);
  bf16* qb   = (bf16*)(ws + 1 * BUF);          // [B,H,S,D] (pre-scaled)
  bf16* kb   = (bf16*)(ws + 2 * BUF);          // [B,H,S,D]
  bf16* vtb  = (bf16*)(ws + 3 * BUF);          // [B,H,D,S]
  bf16* tqb  = (bf16*)(ws + 4 * BUF);          // [B,H,S,D] (pre-scaled)
  bf16* attb = (bf16*)(ws + 5 * BUF);          // [B,S,E] flash output
  bf16* nrmb = qb;                             // alias: qb dead after flash
  uint8_t* wp = ws + 6 * BUF;
  bf16* Wqb  = (bf16*)(wp + 0 * WBUF);
  bf16* Wkb  = (bf16*)(wp + 1 * WBUF);
  bf16* Wvb  = (bf16*)(wp + 2 * WBUF);
  bf16* Wtqb = (bf16*)(wp + 3 * WBUF);
  bf16* Wob  = (bf16*)(wp + 4 * WBUF);
  float* tkb = (float*)(wp + 5 * WBUF);               // [8][E] f32
  float* tvb = (float*)(wp + 5 * WBUF + 128 * 1024);  // [8][E] f32

  // --- convert f32 -> bf16 (x + batched 5 weights) ---
  const int WN8 = E_DIM * E_DIM / 8;   // 524288
  const int XN8 = NTOK * E_DIM / 8;    // 1048576
  cvt_f32_bf16_kernel<<<dim3(2048), 256, 0, stream>>>(x, xb, XN8);
  CvtArgs ca;
  ca.src[0] = Wq;  ca.dst[0] = Wqb;
  ca.src[1] = Wk;  ca.dst[1] = Wkb;
  ca.src[2] = Wv;  ca.dst[2] = Wvb;
  ca.src[3] = Wtq; ca.dst[3] = Wtqb;
  ca.src[4] = Wo;  ca.dst[4] = Wob;
  cvt5_kernel<<<dim3(1024, 5), 256, 0, stream>>>(ca, WN8);

  // --- projections (Q and TQ pre-scaled by 1/sqrt(D)*log2e) ---
  ProjArgs pa;
  pa.W[0] = Wqb;  pa.bias[0] = bq;  pa.out[0] = qb;  pa.mode[0] = 1; pa.scale[0] = QSCALE;
  pa.W[1] = Wkb;  pa.bias[1] = bk;  pa.out[1] = kb;  pa.mode[1] = 1; pa.scale[1] = 1.0f;
  pa.W[2] = Wvb;  pa.bias[2] = bv;  pa.out[2] = vtb; pa.mode[2] = 2; pa.scale[2] = 1.0f;
  pa.W[3] = Wtqb; pa.bias[3] = btq; pa.out[3] = tqb; pa.mode[3] = 1; pa.scale[3] = QSCALE;
  gemm256_kernel<<<dim3(16 * 8 * 4), 512, 0, stream>>>(xb, pa, 16, 8);

  slots_proj_kernel<<<dim3(E_DIM / 256, NSLOT, 2), 256, 0, stream>>>(
      slots, Wtk, btk, Wtv, btv, tkb, tvb);

  // --- attention streams ---
  flash_attn_kernel<<<dim3((SEQ / 256) * BATCH * HEADS), 512, 0, stream>>>(
      qb, kb, vtb, attb);
  thought_ln_kernel<<<dim3(NTOK), 256, 0, stream>>>(
      tqb, tkb, tvb, attb, gamma, beta, nrmb);

  // --- output projection (f32 out) ---
  ProjArgs po;
  po.W[0] = Wob; po.bias[0] = bo; po.out[0] = d_out; po.mode[0] = 0; po.scale[0] = 1.0f;
  po.W[1] = po.W[2] = po.W[3] = Wob;
  po.bias[1] = po.bias[2] = po.bias[3] = bo;
  po.out[1] = po.out[2] = po.out[3] = d_out;
  po.mode[1] = po.mode[2] = po.mode[3] = 0;
  po.scale[1] = po.scale[2] = po.scale[3] = 1.0f;
  gemm_nt_kernel<<<dim3(NTOK / 128, E_DIM / 128, 1), 256, 0, stream>>>(
      nrmb, po, NTOK, E_DIM, E_DIM);
}

// Round 12
// 431.957 us; speedup vs baseline: 1.2717x; 1.0387x over previous
//
#include <hip/hip_runtime.h>
#include <hip/hip_bf16.h>
#include <stdint.h>

typedef __bf16 bf16;
typedef __bf16 bf16x8 __attribute__((ext_vector_type(8)));
typedef __bf16 bf16x4 __attribute__((ext_vector_type(4)));
typedef float f32x4 __attribute__((ext_vector_type(4)));
typedef float f32x16 __attribute__((ext_vector_type(16)));
typedef uint32_t u32x2 __attribute__((ext_vector_type(2)));
typedef uint32_t u32x4 __attribute__((ext_vector_type(4)));

#define E_DIM 2048
#define HEADS 16
#define HD 128
#define SEQ 2048
#define BATCH 2
#define NTOK 4096
#define NSLOT 8

// 1/sqrt(128) * log2(e): folded into Q / TQ at projection time
#define QSCALE (0.08838834764831845f * 1.4426950408889634f)

#define WAITV(N) asm volatile("s_waitcnt vmcnt(" #N ")" ::: "memory")

__device__ __forceinline__ void gload_lds16(const void* g, void* lds) {
  __builtin_amdgcn_global_load_lds(
      (const __attribute__((address_space(1))) uint32_t*)g,
      (__attribute__((address_space(3))) uint32_t*)lds, 16, 0, 0);
}

// ---------------- f32 -> bf16 convert ----------------
__global__ __launch_bounds__(256) void cvt_f32_bf16_kernel(
    const float* __restrict__ src, bf16* __restrict__ dst, int n8)
{
  for (int i = blockIdx.x * 256 + threadIdx.x; i < n8; i += gridDim.x * 256) {
    const f32x4 a = *(const f32x4*)(src + i * 8);
    const f32x4 b = *(const f32x4*)(src + i * 8 + 4);
    bf16x8 o;
#pragma unroll
    for (int j = 0; j < 4; j++) { o[j] = (bf16)a[j]; o[4 + j] = (bf16)b[j]; }
    *(bf16x8*)(dst + i * 8) = o;
  }
}

struct CvtArgs { const float* src[5]; bf16* dst[5]; };

__global__ __launch_bounds__(256) void cvt5_kernel(CvtArgs a, int n8)
{
  const float* __restrict__ src = a.src[blockIdx.y];
  bf16* __restrict__ dst = a.dst[blockIdx.y];
  for (int i = blockIdx.x * 256 + threadIdx.x; i < n8; i += gridDim.x * 256) {
    const f32x4 x = *(const f32x4*)(src + i * 8);
    const f32x4 y = *(const f32x4*)(src + i * 8 + 4);
    bf16x8 o;
#pragma unroll
    for (int j = 0; j < 4; j++) { o[j] = (bf16)x[j]; o[4 + j] = (bf16)y[j]; }
    *(bf16x8*)(dst + i * 8) = o;
  }
}

struct ProjArgs {
  const bf16* W[4];
  const float* bias[4];
  void* out[4];
  int mode[4];     // 0: f32 row-major [M][N=2048]; 1: bf16 [B,H,S,D]; 2: bf16 [B,H,D,S]
  float scale[4];  // applied AFTER bias
};

// ---------------- 256x256 NT GEMM, 4-phase/K-tile, 3 barriers/tile, vmcnt(6) ------
// Same data layout/ledger as round-10, with the 5 unnecessary barriers removed:
//  - each phase's MFMA forces lgkm-completion of that phase's ds_reads before the
//    wave proceeds, so by q0's END barrier all waves' B reads are complete ->
//    B0/B1(t+2) stages at q1/q2 need no further barrier;
//  - q3 keeps its mid-barrier (all A0 reads done) before staging A0(t+2);
//  - tile-end barrier carries the counted vmcnt(6) (never drains in steady state).
// Stage stream per tile t: q0:A1(t+1) | q1:B0(t+2) | q2:B1(t+2) | q3:A0(t+2);
// vmcnt(6) at tile end retires exactly tile t+1's 4 units (ledger unchanged).
__global__ __launch_bounds__(512, 2) void gemm256_kernel(
    const bf16* __restrict__ A, ProjArgs pa, int nbm, int nbn)
{
  __shared__ char As_[2 * 32768];
  __shared__ char Bs_[2 * 32768];

  const int nwg = gridDim.x;
  const int qch = nwg >> 3;
  const int wg = (blockIdx.x & 7) * qch + (blockIdx.x >> 3);
  const int bm = wg % nbm;
  const int rest = wg / nbm;
  const int bn = rest % nbn;
  const int z = rest / nbn;

  const bf16* __restrict__ W = pa.W[z];
  const float* __restrict__ bias = pa.bias[z];
  void* __restrict__ out = pa.out[z];
  const int mode = pa.mode[z];
  const float scale = pa.scale[z];

  const int tid = threadIdx.x;
  const int lane = tid & 63;
  const int w = tid >> 6;          // 0..7
  const int wr = w >> 2;           // 0..1 (M)
  const int wc = w & 3;            // 0..3 (N)
  const int g = lane >> 4, c = lane & 15;

  const int srow = tid >> 3;                       // 0..63
  const int sslot = tid & 7;
  const int scol = (sslot ^ (srow & 7)) * 8;
  const bf16* Abase = A + (size_t)(bm * 256) * 2048;
  const bf16* Bbase = W + (size_t)(bn * 256) * 2048;

  auto stageU = [&](const bf16* gbase, char* lds, int T, int u) {
    char* dst = lds + (T & 1) * 32768 + u * 16384;
    const int k0 = T * 64;
#pragma unroll
    for (int j = 0; j < 2; j++) {
      const int r = u * 128 + srow + j * 64;
      gload_lds16(gbase + (size_t)r * 2048 + k0 + scol,
                  dst + (size_t)(srow + j * 64) * 128 + sslot * 16);
    }
  };

  f32x4 acc[8][4] = {};
  bf16x8 bfr[4][2];                // B fragments, held across the 4 phases

  // prologue: units t0:B0,B1,A0,A1, t1:B0,B1,A0 (14 loads); retire t0 (vmcnt 6)
  stageU(Bbase, Bs_, 0, 0); stageU(Bbase, Bs_, 0, 1);
  stageU(Abase, As_, 0, 0); stageU(Abase, As_, 0, 1);
  stageU(Bbase, Bs_, 1, 0); stageU(Bbase, Bs_, 1, 1);
  stageU(Abase, As_, 1, 0);
  WAITV(6);
  __builtin_amdgcn_s_barrier();

  const int NT = 2048 / 64;        // 32
  for (int t = 0; t < NT; t++) {
    const int d = t & 1;
    const char* Aq = As_ + d * 32768;
    const char* Bq = Bs_ + d * 32768;
#pragma unroll
    for (int q = 0; q < 4; q++) {
      // --- ds_read phase fragments ---
      bf16x8 af[2][2];
      if (q == 0) {
#pragma unroll
        for (int n = 0; n < 4; n++)
#pragma unroll
          for (int kk = 0; kk < 2; kk++) {
            const int row = wc * 64 + n * 16 + c;
            bfr[n][kk] = *(const bf16x8*)(Bq + (size_t)row * 128 +
                                          (((kk * 4 + g) ^ (c & 7)) * 16));
          }
      }
#pragma unroll
      for (int mi2 = 0; mi2 < 2; mi2++)
#pragma unroll
        for (int kk = 0; kk < 2; kk++) {
          const int row = wr * 128 + (q * 2 + mi2) * 16 + c;
          af[mi2][kk] = *(const bf16x8*)(Aq + (size_t)row * 128 +
                                         (((kk * 4 + g) ^ (c & 7)) * 16));
        }

      // --- stage one unit (targets dead since an earlier barrier) ---
      if (q == 0)      { if (t + 1 < NT) stageU(Abase, As_, t + 1, 1); }   // dbuf d^1; dead since t-1 end-barrier
      else if (q == 1) { if (t + 2 < NT) stageU(Bbase, Bs_, t + 2, 0); }   // B dead since q0-end barrier
      else if (q == 2) { if (t + 2 < NT) stageU(Bbase, Bs_, t + 2, 1); }
      else {
        __builtin_amdgcn_s_barrier();                                      // all A0 reads done
        if (t + 2 < NT) stageU(Abase, As_, t + 2, 0);
      }

      // --- MFMA quadrant (forces lgkm completion of this phase's reads) ---
      __builtin_amdgcn_s_setprio(1);
#pragma unroll
      for (int mi2 = 0; mi2 < 2; mi2++)
#pragma unroll
        for (int n = 0; n < 4; n++)
#pragma unroll
          for (int kk = 0; kk < 2; kk++)
            acc[q * 2 + mi2][n] = __builtin_amdgcn_mfma_f32_16x16x32_bf16(
                af[mi2][kk], bfr[n][kk], acc[q * 2 + mi2][n], 0, 0, 0);
      __builtin_amdgcn_s_setprio(0);

      // --- barriers: q0-end (protect B stages), q3-end (vmcnt + tile pacing) ---
      if (q == 0) {
        __builtin_amdgcn_s_barrier();
      } else if (q == 3) {
        if (t < NT - 2)       { WAITV(6); }
        else if (t == NT - 2) { WAITV(0); }
        __builtin_amdgcn_s_barrier();
      }
    }
  }

  // epilogue: D[r][c]: col = lane&15, row = (lane>>4)*4 + j  (per 16x16 frag)
#pragma unroll
  for (int mi = 0; mi < 8; mi++) {
#pragma unroll
    for (int n = 0; n < 4; n++) {
      const int col = bn * 256 + wc * 64 + n * 16 + c;
      const float bv = bias[col];
#pragma unroll
      for (int j = 0; j < 4; j++) {
        const int row = bm * 256 + wr * 128 + mi * 16 + g * 4 + j;
        const float v = (acc[mi][n][j] + bv) * scale;
        if (mode == 0) {
          ((float*)out)[(size_t)row * E_DIM + col] = v;
        } else {
          const int b = row >> 11, s = row & 2047;
          const int h = col >> 7, d2 = col & 127;
          size_t idx;
          if (mode == 1) idx = (((size_t)(b * HEADS + h)) * SEQ + s) * HD + d2;
          else           idx = (((size_t)(b * HEADS + h)) * HD + d2) * SEQ + s;
          ((bf16*)out)[idx] = (bf16)v;
        }
      }
    }
  }
}

// ---------------- 128x128 NT GEMM (final projection) ----------
__global__ __launch_bounds__(256) void gemm_nt_kernel(
    const bf16* __restrict__ A, ProjArgs pa, int M, int N, int K)
{
  __shared__ bf16 As[2][128 * 32];
  __shared__ bf16 Bs[2][128 * 32];

  const int z = blockIdx.z;
  const bf16* __restrict__ W = pa.W[z];
  const float* __restrict__ bias = pa.bias[z];
  void* __restrict__ out = pa.out[z];
  const int mode = pa.mode[z];
  const float scale = pa.scale[z];

  const int tid = threadIdx.x;
  const int lane = tid & 63;
  const int w = tid >> 6;
  const int wr = w >> 1, wc = w & 1;
  const int g = lane >> 4, c = lane & 15;
  const int bm = blockIdx.x, bn = blockIdx.y;

  f32x4 acc[4][4] = {};

  const int srow = lane >> 2;          // 0..15
  const int scol = (lane & 3) * 8;     // 0,8,16,24
  const bf16* Ab = A + (size_t)(bm * 128 + srow) * K + scol;
  const bf16* Wb = W + (size_t)(bn * 128 + srow) * K + scol;

  auto stage = [&](int k0, int buf) {
#pragma unroll
    for (int i = 0; i < 2; ++i) {
      const int chunk = w * 2 + i;
      gload_lds16(Ab + (size_t)(chunk * 16) * K + k0, (char*)(&As[buf][0]) + chunk * 1024);
      gload_lds16(Wb + (size_t)(chunk * 16) * K + k0, (char*)(&Bs[buf][0]) + chunk * 1024);
    }
  };

  stage(0, 0);
  __syncthreads();
  int cur = 0;

  for (int k0 = 0; k0 < K; k0 += 32) {
    if (k0 + 32 < K) stage(k0 + 32, cur ^ 1);
    bf16x8 af[4], bfr[4];
#pragma unroll
    for (int m = 0; m < 4; m++)
      af[m] = *(const bf16x8*)(&As[cur][0] + (wr * 64 + m * 16 + c) * 32 + g * 8);
#pragma unroll
    for (int n = 0; n < 4; n++)
      bfr[n] = *(const bf16x8*)(&Bs[cur][0] + (wc * 64 + n * 16 + c) * 32 + g * 8);
#pragma unroll
    for (int m = 0; m < 4; m++)
#pragma unroll
      for (int n = 0; n < 4; n++)
        acc[m][n] = __builtin_amdgcn_mfma_f32_16x16x32_bf16(af[m], bfr[n], acc[m][n], 0, 0, 0);
    __syncthreads();
    cur ^= 1;
  }

#pragma unroll
  for (int m = 0; m < 4; m++) {
#pragma unroll
    for (int n = 0; n < 4; n++) {
      const int col = bn * 128 + wc * 64 + n * 16 + c;
      const float bv = bias[col];
#pragma unroll
      for (int j = 0; j < 4; j++) {
        const int row = bm * 128 + wr * 64 + m * 16 + g * 4 + j;
        const float v = (acc[m][n][j] + bv) * scale;
        if (mode == 0) {
          ((float*)out)[(size_t)row * N + col] = v;
        } else {
          const int b = row >> 11, s = row & 2047;
          const int h = col >> 7, d = col & 127;
          size_t idx;
          if (mode == 1) idx = (((size_t)(b * HEADS + h)) * SEQ + s) * HD + d;
          else           idx = (((size_t)(b * HEADS + h)) * HD + d) * SEQ + s;
          ((bf16*)out)[idx] = (bf16)v;
        }
      }
    }
  }
}

// ---------------- slots projections ----------------
__global__ __launch_bounds__(256) void slots_proj_kernel(
    const float* __restrict__ slots,
    const float* __restrict__ Wk, const float* __restrict__ bk,
    const float* __restrict__ Wv, const float* __restrict__ bv,
    float* __restrict__ tk, float* __restrict__ tv)
{
  const int col = blockIdx.x * 256 + threadIdx.x;
  const int slot = blockIdx.y;
  const int mat = blockIdx.z;
  const float* W = mat ? Wv : Wk;
  const float* bias = mat ? bv : bk;
  float* out = mat ? tv : tk;
  const float* xr = slots + (size_t)slot * E_DIM;
  const float* wr = W + (size_t)col * E_DIM;
  float acc = 0.f;
  for (int k = 0; k < E_DIM; k += 4) {
    const f32x4 a = *(const f32x4*)(xr + k);
    const f32x4 b4 = *(const f32x4*)(wr + k);
#pragma unroll
    for (int i = 0; i < 4; i++) acc += a[i] * b4[i];
  }
  out[(size_t)slot * E_DIM + col] = acc + bias[col];
}

// ---------------- flash attention: 8-wave 32x32, T15 deferred-PV pipeline ----------------
// (round-11 measured-best version, verbatim)
__global__ __launch_bounds__(512) void flash_attn_kernel(
    const bf16* __restrict__ Qg, const bf16* __restrict__ Kg,
    const bf16* __restrict__ Vtg, bf16* __restrict__ Og)
{
  __shared__ char Ks[3][64 * 256];    // [kv][d] bf16, 256B rows, slot ^= r&15
  __shared__ char Vs[3][128 * 128];   // [d][kv] bf16, 128B rows, slot ^= r&7

  const int orig = blockIdx.x;                 // 256 blocks
  const int logical = (orig & 7) * 32 + (orig >> 3);   // XCD swizzle
  const int qt = logical & 7;
  const int bh = logical >> 3;

  const int tid = threadIdx.x;
  const int lane = tid & 63;
  const int w = tid >> 6;          // 0..7
  const int q = lane & 31;
  const int hi = lane >> 5;
  const int b = bh >> 4, h = bh & 15;
  const int q0 = qt * 256 + w * 32;

  const bf16* Qb = Qg + ((size_t)bh * SEQ + q0) * HD;
  const bf16* Kb = Kg + (size_t)bh * SEQ * HD;
  const bf16* Vb = Vtg + (size_t)bh * HD * SEQ;

  auto stage = [&](int kv0, int buf) {
#pragma unroll
    for (int i = 0; i < 2; i++) {
      const int p = (tid + i * 512) * 16;
      { const int r = p >> 8; const int s16 = (p >> 4) & 15;
        gload_lds16(Kb + (size_t)(kv0 + r) * HD + (s16 ^ (r & 15)) * 8, &Ks[0][0] + buf * 16384 + p); }
      { const int r = p >> 7; const int s8 = (p >> 4) & 7;
        gload_lds16(Vb + (size_t)r * SEQ + kv0 + (s8 ^ (r & 7)) * 8, &Vs[0][0] + buf * 16384 + p); }
    }
  };

  bf16x8 qf[8];
#pragma unroll
  for (int kc = 0; kc < 8; kc++)
    qf[kc] = *(const bf16x8*)(Qb + (size_t)q * HD + kc * 16 + hi * 8);

  f32x16 o[4] = {};                  // O^T[d][q]
  float mrun = -1e30f, lsum = 0.f;
  bf16x8 pbo[2][2];                  // previous tile's P fragments (PV deferred)

  stage(0, 0);
  __syncthreads();

  int prv = 2, cur = 0, nxt = 1;     // rotating buffer indices
  const int NT = SEQ / 64;           // 32

  for (int t = 0; t < NT; t++) {
    if (t + 1 < NT) stage((t + 1) * 64, nxt);

    // S^T[kv][q] = K(t) . Q^T
    f32x16 st[2] = {};
    const char* Kc = &Ks[0][0] + cur * 16384;
    __builtin_amdgcn_s_setprio(1);
#pragma unroll
    for (int kc = 0; kc < 8; kc++) {
#pragma unroll
      for (int blk = 0; blk < 2; blk++) {
        const int rt = blk * 32 + q;
        const int sl = (2 * kc + hi) ^ (rt & 15);
        const bf16x8 kf = *(const bf16x8*)(Kc + rt * 256 + sl * 16);
        st[blk] = __builtin_amdgcn_mfma_f32_32x32x16_bf16(kf, qf[kc], st[blk], 0, 0, 0);
      }
    }
    __builtin_amdgcn_s_setprio(0);

    // max + defer-max decision
    float tm[16];
#pragma unroll
    for (int i = 0; i < 16; i++) tm[i] = fmaxf(st[0][i], st[1][i]);
#pragma unroll
    for (int s2 = 8; s2 > 0; s2 >>= 1)
#pragma unroll
      for (int i = 0; i < 8; i++) if (i < s2) tm[i] = fmaxf(tm[i], tm[i + s2]);
    float lm = tm[0];
    lm = fmaxf(lm, __shfl_xor(lm, 32));
    float fsc = 1.0f;
    const bool resc = __any(lm > mrun + 8.0f);
    if (resc) {
      const float mn = fmaxf(mrun, lm);
      fsc = exp2f(mrun - mn);
      mrun = mn;
    }

    // --- independent region: softmax-core(t) [VALU/TRANS] + PV(t-1) [MFMA] ---
    float ps0 = 0.f, ps1 = 0.f, ps2 = 0.f, ps3 = 0.f;
#pragma unroll
    for (int blk = 0; blk < 2; blk++)
#pragma unroll
      for (int i = 0; i < 16; i += 4) {
        const float p0 = exp2f(st[blk][i]     - mrun);
        const float p1 = exp2f(st[blk][i + 1] - mrun);
        const float p2 = exp2f(st[blk][i + 2] - mrun);
        const float p3 = exp2f(st[blk][i + 3] - mrun);
        st[blk][i] = p0; st[blk][i + 1] = p1; st[blk][i + 2] = p2; st[blk][i + 3] = p3;
        ps0 += p0; ps1 += p1; ps2 += p2; ps3 += p3;
      }
    lsum = lsum * fsc + ((ps0 + ps1) + (ps2 + ps3));

    bf16x8 pbn[2][2];
#pragma unroll
    for (int blk = 0; blk < 2; blk++)
#pragma unroll
      for (int c2 = 0; c2 < 2; c2++) {
        bf16x4 Lv, Hv;
#pragma unroll
        for (int i = 0; i < 4; i++) {
          Lv[i] = (bf16)st[blk][8 * c2 + i];
          Hv[i] = (bf16)st[blk][8 * c2 + 4 + i];
        }
        const u32x2 Lu = __builtin_bit_cast(u32x2, Lv);
        const u32x2 Hu = __builtin_bit_cast(u32x2, Hv);
        const uint32_t s0 = hi ? Lu.x : Hu.x;
        const uint32_t s1 = hi ? Lu.y : Hu.y;
        const uint32_t x0 = (uint32_t)__shfl_xor((int)s0, 32);
        const uint32_t x1 = (uint32_t)__shfl_xor((int)s1, 32);
        u32x4 bv;
        bv.x = hi ? x0 : Lu.x;
        bv.y = hi ? x1 : Lu.y;
        bv.z = hi ? Hu.x : x0;
        bv.w = hi ? Hu.y : x1;
        pbn[blk][c2] = __builtin_bit_cast(bf16x8, bv);
      }

    if (t > 0) {   // PV(t-1): o += V(t-1)^T . P(t-1)^T
      const char* Vc = &Vs[0][0] + prv * 16384;
#pragma unroll
      for (int db = 0; db < 4; db++) {
        const int rt = db * 32 + q;
#pragma unroll
        for (int blk = 0; blk < 2; blk++)
#pragma unroll
          for (int c2 = 0; c2 < 2; c2++) {
            const int sl = (blk * 4 + c2 * 2 + hi) ^ (rt & 7);
            const bf16x8 vf = *(const bf16x8*)(Vc + rt * 128 + sl * 16);
            o[db] = __builtin_amdgcn_mfma_f32_32x32x16_bf16(vf, pbo[blk][c2], o[db], 0, 0, 0);
          }
      }
    }

    // rescale AFTER PV(t-1): o now complete through t-1 at scale m(t-1)
    if (resc) {
#pragma unroll
      for (int db = 0; db < 4; db++)
#pragma unroll
        for (int i = 0; i < 16; i++) o[db][i] *= fsc;
    }

#pragma unroll
    for (int blk = 0; blk < 2; blk++)
#pragma unroll
      for (int c2 = 0; c2 < 2; c2++) pbo[blk][c2] = pbn[blk][c2];

    __syncthreads();   // drains own staging vmcnt; all waves' reads of prv/cur done
    const int tmp = prv; prv = cur; cur = nxt; nxt = tmp;
  }

  // epilogue: PV(NT-1)
  {
    const char* Vc = &Vs[0][0] + prv * 16384;
#pragma unroll
    for (int db = 0; db < 4; db++) {
      const int rt = db * 32 + q;
#pragma unroll
      for (int blk = 0; blk < 2; blk++)
#pragma unroll
        for (int c2 = 0; c2 < 2; c2++) {
          const int sl = (blk * 4 + c2 * 2 + hi) ^ (rt & 7);
          const bf16x8 vf = *(const bf16x8*)(Vc + rt * 128 + sl * 16);
          o[db] = __builtin_amdgcn_mfma_f32_32x32x16_bf16(vf, pbo[blk][c2], o[db], 0, 0, 0);
        }
    }
  }

  // normalize + store
  const float lt = lsum + __shfl_xor(lsum, 32);
  const float linv = 1.0f / lt;
  bf16* Orow = Og + ((size_t)b * SEQ + q0 + q) * E_DIM + h * HD;
#pragma unroll
  for (int db = 0; db < 4; db++)
#pragma unroll
    for (int g4 = 0; g4 < 4; g4++) {
      bf16x4 ov;
#pragma unroll
      for (int i = 0; i < 4; i++) ov[i] = (bf16)(o[db][g4 * 4 + i] * linv);
      *(bf16x4*)(Orow + db * 32 + g4 * 8 + hi * 4) = ov;
    }
}

// ---------------- fused thought cross-attn + LayerNorm ----------------
__global__ __launch_bounds__(256) void thought_ln_kernel(
    const bf16* __restrict__ TQ, const float* __restrict__ TK,
    const float* __restrict__ TV, const bf16* __restrict__ ATT,
    const float* __restrict__ gamma, const float* __restrict__ beta,
    bf16* __restrict__ Y)
{
  __shared__ float wsum[4], wsq[4];
  const int tid = threadIdx.x;
  const int lane = tid & 63;
  const int w = tid >> 6;
  const int tok = blockIdx.x;            // b*SEQ + s
  const int b = tok >> 11, s = tok & 2047;
  const int e0 = tid * 8;
  const int h = e0 >> 7;
  const int d0 = e0 & 127;

  const bf16x8 av = *(const bf16x8*)(ATT + (size_t)tok * E_DIM + e0);
  float v[8];
#pragma unroll
  for (int i = 0; i < 8; i++) v[i] = (float)av[i];

  const bf16x8 qv8 = *(const bf16x8*)(TQ + (((size_t)(b * HEADS + h)) * SEQ + s) * HD + d0);
  float qv[8];
#pragma unroll
  for (int i = 0; i < 8; i++) qv[i] = (float)qv8[i];

  float dts[NSLOT];
#pragma unroll
  for (int sl = 0; sl < NSLOT; sl++) {
    const float* tkr = TK + (size_t)sl * E_DIM + e0;
    const f32x4 k0 = *(const f32x4*)(tkr);
    const f32x4 k1 = *(const f32x4*)(tkr + 4);
    float dp = 0.f;
#pragma unroll
    for (int i = 0; i < 4; i++) dp += qv[i] * k0[i] + qv[4 + i] * k1[i];
    dp += __shfl_xor(dp, 1);
    dp += __shfl_xor(dp, 2);
    dp += __shfl_xor(dp, 4);
    dp += __shfl_xor(dp, 8);
    dts[sl] = dp;
  }
  float mx = dts[0];
#pragma unroll
  for (int sl = 1; sl < NSLOT; sl++) mx = fmaxf(mx, dts[sl]);
  float p[NSLOT], den = 0.f;
#pragma unroll
  for (int sl = 0; sl < NSLOT; sl++) { p[sl] = exp2f(dts[sl] - mx); den += p[sl]; }
  const float dinv = 1.0f / den;
#pragma unroll
  for (int sl = 0; sl < NSLOT; sl++) {
    const float pn = p[sl] * dinv;
    const float* tvr = TV + (size_t)sl * E_DIM + e0;
    const f32x4 v0 = *(const f32x4*)(tvr);
    const f32x4 v1 = *(const f32x4*)(tvr + 4);
#pragma unroll
    for (int i = 0; i < 4; i++) { v[i] += pn * v0[i]; v[4 + i] += pn * v1[i]; }
  }

  float sm = 0.f, sq = 0.f;
#pragma unroll
  for (int i = 0; i < 8; i++) { sm += v[i]; sq += v[i] * v[i]; }
#pragma unroll
  for (int d = 1; d < 64; d <<= 1) { sm += __shfl_xor(sm, d); sq += __shfl_xor(sq, d); }
  if (lane == 0) { wsum[w] = sm; wsq[w] = sq; }
  __syncthreads();
  const float ts = wsum[0] + wsum[1] + wsum[2] + wsum[3];
  const float tq2 = wsq[0] + wsq[1] + wsq[2] + wsq[3];
  const float mean = ts * (1.f / E_DIM);
  const float var = tq2 * (1.f / E_DIM) - mean * mean;
  const float rstd = rsqrtf(var + 1e-5f);
  const f32x4 g0 = *(const f32x4*)(gamma + e0);
  const f32x4 g1 = *(const f32x4*)(gamma + e0 + 4);
  const f32x4 b0 = *(const f32x4*)(beta + e0);
  const f32x4 b1 = *(const f32x4*)(beta + e0 + 4);
  bf16x8 outv;
#pragma unroll
  for (int i = 0; i < 4; i++) {
    outv[i]     = (bf16)((v[i]     - mean) * rstd * g0[i] + b0[i]);
    outv[4 + i] = (bf16)((v[4 + i] - mean) * rstd * g1[i] + b1[i]);
  }
  *(bf16x8*)(Y + (size_t)tok * E_DIM + e0) = outv;
}

extern "C" void kernel_launch(void* const* d_in, const int* in_sizes, int n_in,
                              void* d_out, int out_size, void* d_ws, size_t ws_size,
                              hipStream_t stream) {
  (void)in_sizes; (void)n_in; (void)out_size; (void)ws_size;
  const float* x     = (const float*)d_in[0];
  const float* slots = (const float*)d_in[1];
  const float* Wq  = (const float*)d_in[2];   const float* bq  = (const float*)d_in[3];
  const float* Wk  = (const float*)d_in[4];   const float* bk  = (const float*)d_in[5];
  const float* Wv  = (const float*)d_in[6];   const float* bv  = (const float*)d_in[7];
  const float* Wtq = (const float*)d_in[8];   const float* btq = (const float*)d_in[9];
  const float* Wtk = (const float*)d_in[10];  const float* btk = (const float*)d_in[11];
  const float* Wtv = (const float*)d_in[12];  const float* btv = (const float*)d_in[13];
  const float* Wo  = (const float*)d_in[14];  const float* bo  = (const float*)d_in[15];
  const float* gamma = (const float*)d_in[16];
  const float* beta  = (const float*)d_in[17];

  uint8_t* ws = (uint8_t*)d_ws;
  const size_t BUF  = (size_t)NTOK * E_DIM * sizeof(bf16);    // 16 MiB
  const size_t WBUF = (size_t)E_DIM * E_DIM * sizeof(bf16);   // 8 MiB
  bf16* xb   = (bf16*)(ws + 0 * BUF);
  bf16* qb   = (bf16*)(ws + 1 * BUF);          // [B,H,S,D] (pre-scaled)
  bf16* kb   = (bf16*)(ws + 2 * BUF);          // [B,H,S,D]
  bf16* vtb  = (bf16*)(ws + 3 * BUF);          // [B,H,D,S]
  bf16* tqb  = (bf16*)(ws + 4 * BUF);          // [B,H,S,D] (pre-scaled)
  bf16* attb = (bf16*)(ws + 5 * BUF);          // [B,S,E] flash output
  bf16* nrmb = qb;                             // alias: qb dead after flash
  uint8_t* wp = ws + 6 * BUF;
  bf16* Wqb  = (bf16*)(wp + 0 * WBUF);
  bf16* Wkb  = (bf16*)(wp + 1 * WBUF);
  bf16* Wvb  = (bf16*)(wp + 2 * WBUF);
  bf16* Wtqb = (bf16*)(wp + 3 * WBUF);
  bf16* Wob  = (bf16*)(wp + 4 * WBUF);
  float* tkb = (float*)(wp + 5 * WBUF);               // [8][E] f32
  float* tvb = (float*)(wp + 5 * WBUF + 128 * 1024);  // [8][E] f32

  // --- convert f32 -> bf16 (x + batched 5 weights) ---
  const int WN8 = E_DIM * E_DIM / 8;   // 524288
  const int XN8 = NTOK * E_DIM / 8;    // 1048576
  cvt_f32_bf16_kernel<<<dim3(2048), 256, 0, stream>>>(x, xb, XN8);
  CvtArgs ca;
  ca.src[0] = Wq;  ca.dst[0] = Wqb;
  ca.src[1] = Wk;  ca.dst[1] = Wkb;
  ca.src[2] = Wv;  ca.dst[2] = Wvb;
  ca.src[3] = Wtq; ca.dst[3] = Wtqb;
  ca.src[4] = Wo;  ca.dst[4] = Wob;
  cvt5_kernel<<<dim3(1024, 5), 256, 0, stream>>>(ca, WN8);

  // --- projections (Q and TQ pre-scaled by 1/sqrt(D)*log2e) ---
  ProjArgs pa;
  pa.W[0] = Wqb;  pa.bias[0] = bq;  pa.out[0] = qb;  pa.mode[0] = 1; pa.scale[0] = QSCALE;
  pa.W[1] = Wkb;  pa.bias[1] = bk;  pa.out[1] = kb;  pa.mode[1] = 1; pa.scale[1] = 1.0f;
  pa.W[2] = Wvb;  pa.bias[2] = bv;  pa.out[2] = vtb; pa.mode[2] = 2; pa.scale[2] = 1.0f;
  pa.W[3] = Wtqb; pa.bias[3] = btq; pa.out[3] = tqb; pa.mode[3] = 1; pa.scale[3] = QSCALE;
  gemm256_kernel<<<dim3(16 * 8 * 4), 512, 0, stream>>>(xb, pa, 16, 8);

  slots_proj_kernel<<<dim3(E_DIM / 256, NSLOT, 2), 256, 0, stream>>>(
      slots, Wtk, btk, Wtv, btv, tkb, tvb);

  // --- attention streams ---
  flash_attn_kernel<<<dim3((SEQ / 256) * BATCH * HEADS), 512, 0, stream>>>(
      qb, kb, vtb, attb);
  thought_ln_kernel<<<dim3(NTOK), 256, 0, stream>>>(
      tqb, tkb, tvb, attb, gamma, beta, nrmb);

  // --- output projection (f32 out) ---
  ProjArgs po;
  po.W[0] = Wob; po.bias[0] = bo; po.out[0] = d_out; po.mode[0] = 0; po.scale[0] = 1.0f;
  po.W[1] = po.W[2] = po.W[3] = Wob;
  po.bias[1] = po.bias[2] = po.bias[3] = bo;
  po.out[1] = po.out[2] = po.out[3] = d_out;
  po.mode[1] = po.mode[2] = po.mode[3] = 0;
  po.scale[1] = po.scale[2] = po.scale[3] = 1.0f;
  gemm_nt_kernel<<<dim3(NTOK / 128, E_DIM / 128, 1), 256, 0, stream>>>(
      nrmb, po, NTOK, E_DIM, E_DIM);
}

// Round 13
// 423.172 us; speedup vs baseline: 1.2981x; 1.0208x over previous
//
#include <hip/hip_runtime.h>
#include <hip/hip_bf16.h>
#include <stdint.h>

typedef __bf16 bf16;
typedef __bf16 bf16x8 __attribute__((ext_vector_type(8)));
typedef __bf16 bf16x4 __attribute__((ext_vector_type(4)));
typedef float f32x4 __attribute__((ext_vector_type(4)));
typedef float f32x16 __attribute__((ext_vector_type(16)));
typedef uint32_t u32x2 __attribute__((ext_vector_type(2)));
typedef uint32_t u32x4 __attribute__((ext_vector_type(4)));

#define E_DIM 2048
#define HEADS 16
#define HD 128
#define SEQ 2048
#define BATCH 2
#define NTOK 4096
#define NSLOT 8

#define QSCALE (0.08838834764831845f * 1.4426950408889634f)

#define WAITV(N) asm volatile("s_waitcnt vmcnt(" #N ")" ::: "memory")

__device__ __forceinline__ void gload_lds16(const void* g, void* lds) {
  __builtin_amdgcn_global_load_lds(
      (const __attribute__((address_space(1))) uint32_t*)g,
      (__attribute__((address_space(3))) uint32_t*)lds, 16, 0, 0);
}

// ---------------- f32 -> bf16 convert ----------------
__global__ __launch_bounds__(256) void cvt_f32_bf16_kernel(
    const float* __restrict__ src, bf16* __restrict__ dst, int n8)
{
  for (int i = blockIdx.x * 256 + threadIdx.x; i < n8; i += gridDim.x * 256) {
    const f32x4 a = *(const f32x4*)(src + i * 8);
    const f32x4 b = *(const f32x4*)(src + i * 8 + 4);
    bf16x8 o;
#pragma unroll
    for (int j = 0; j < 4; j++) { o[j] = (bf16)a[j]; o[4 + j] = (bf16)b[j]; }
    *(bf16x8*)(dst + i * 8) = o;
  }
}

struct CvtArgs { const float* src[5]; bf16* dst[5]; };

__global__ __launch_bounds__(256) void cvt5_kernel(CvtArgs a, int n8)
{
  const float* __restrict__ src = a.src[blockIdx.y];
  bf16* __restrict__ dst = a.dst[blockIdx.y];
  for (int i = blockIdx.x * 256 + threadIdx.x; i < n8; i += gridDim.x * 256) {
    const f32x4 x = *(const f32x4*)(src + i * 8);
    const f32x4 y = *(const f32x4*)(src + i * 8 + 4);
    bf16x8 o;
#pragma unroll
    for (int j = 0; j < 4; j++) { o[j] = (bf16)x[j]; o[4 + j] = (bf16)y[j]; }
    *(bf16x8*)(dst + i * 8) = o;
  }
}

struct ProjArgs {
  const bf16* W[4];
  const float* bias[4];
  void* out[4];
  int mode[4];     // 1: bf16 [B,H,S,D]; 2: bf16 [B,H,D,S]
  float scale[4];
};

// ---------------- 256x256 NT GEMM, 4-phase/K-tile, 2 barriers/tile, vmcnt(6) ------
// A-unit interleave: A slab u = (row>>6)&1 (u0 = rows {0-63,128-191}, u1 = rest),
// offset-in-slab = (row&63) + ((row>>7)<<6). Both wave-halves finish their u0 rows
// by q1-end -> ONE q1-end barrier legalizes B0/B1/Au0(t+2) stages at q2/q3.
// Stage stream per tile t: q0:Au1(t+1) | q2:B0(t+2) | q3:B1(t+2)+Au0(t+2).
// Tile-end vmcnt(6) retires exactly through Au1(t+1) (3 units stay in flight).
__global__ __launch_bounds__(512, 2) void gemm256_kernel(
    const bf16* __restrict__ A, ProjArgs pa, int nbm, int nbn)
{
  __shared__ char As_[2 * 32768];
  __shared__ char Bs_[2 * 32768];

  const int nwg = gridDim.x;
  const int qch = nwg >> 3;
  const int wg = (blockIdx.x & 7) * qch + (blockIdx.x >> 3);
  const int bm = wg % nbm;
  const int rest = wg / nbm;
  const int bn = rest % nbn;
  const int z = rest / nbn;

  const bf16* __restrict__ W = pa.W[z];
  const float* __restrict__ bias = pa.bias[z];
  void* __restrict__ out = pa.out[z];
  const int mode = pa.mode[z];
  const float scale = pa.scale[z];

  const int tid = threadIdx.x;
  const int lane = tid & 63;
  const int w = tid >> 6;
  const int wr = w >> 2;
  const int wc = w & 3;
  const int g = lane >> 4, c = lane & 15;

  const int srow = tid >> 3;                       // 0..63
  const int sslot = tid & 7;
  const int scol = (sslot ^ (srow & 7)) * 8;
  const bf16* Abase = A + (size_t)(bm * 256) * 2048;
  const bf16* Bbase = W + (size_t)(bn * 256) * 2048;

  // B staging: unit u holds global rows u*128 .. u*128+127 linearly
  auto stageB = [&](int T, int u) {
    char* dst = Bs_ + (T & 1) * 32768 + u * 16384;
    const int k0 = T * 64;
#pragma unroll
    for (int j = 0; j < 2; j++) {
      const int r = u * 128 + srow + j * 64;
      gload_lds16(Bbase + (size_t)r * 2048 + k0 + scol,
                  dst + (size_t)(srow + j * 64) * 128 + sslot * 16);
    }
  };
  // A staging (interleaved units): unit u, j=0 -> global row u*64+srow (slab off srow),
  // j=1 -> global row 128+u*64+srow (slab off 64+srow)
  auto stageA = [&](int T, int u) {
    char* dst = As_ + (T & 1) * 32768 + u * 16384;
    const int k0 = T * 64;
#pragma unroll
    for (int j = 0; j < 2; j++) {
      const int r = j * 128 + u * 64 + srow;
      gload_lds16(Abase + (size_t)r * 2048 + k0 + scol,
                  dst + (size_t)(srow + j * 64) * 128 + sslot * 16);
    }
  };

  f32x4 acc[8][4] = {};
  bf16x8 bfr[4][2];

  // prologue: B0(0),B1(0),Au0(0),Au1(0), B0(1),B1(1),Au0(1); retire tile0 (vmcnt 6)
  stageB(0, 0); stageB(0, 1); stageA(0, 0); stageA(0, 1);
  stageB(1, 0); stageB(1, 1); stageA(1, 0);
  WAITV(6);
  __builtin_amdgcn_s_barrier();

  const int NT = 2048 / 64;        // 32
  for (int t = 0; t < NT; t++) {
    const int d = t & 1;
    const char* Aq = As_ + d * 32768;
    const char* Bq = Bs_ + d * 32768;
#pragma unroll
    for (int q = 0; q < 4; q++) {
      // --- ds_read phase fragments ---
      bf16x8 af[2][2];
      if (q == 0) {
#pragma unroll
        for (int n = 0; n < 4; n++)
#pragma unroll
          for (int kk = 0; kk < 2; kk++) {
            const int row = wc * 64 + n * 16 + c;
            bfr[n][kk] = *(const bf16x8*)(Bq + (size_t)row * 128 +
                                          (((kk * 4 + g) ^ (c & 7)) * 16));
          }
      }
#pragma unroll
      for (int mi2 = 0; mi2 < 2; mi2++)
#pragma unroll
        for (int kk = 0; kk < 2; kk++) {
          const int row = wr * 128 + (q * 2 + mi2) * 16 + c;
          const int slab = (row >> 6) & 1;
          const int aoff = (row & 63) + ((row >> 7) << 6);
          af[mi2][kk] = *(const bf16x8*)(Aq + slab * 16384 + (size_t)aoff * 128 +
                                         (((kk * 4 + g) ^ (c & 7)) * 16));
        }

      // --- stage units (targets dead since an earlier barrier) ---
      if (q == 0)      { if (t + 1 < NT) stageA(t + 1, 1); }     // dbuf d^1, dead since t-1 end
      else if (q == 2) { if (t + 2 < NT) stageB(t + 2, 0); }     // B dead after q0 < q1-end barrier
      else if (q == 3) { if (t + 2 < NT) { stageB(t + 2, 1); stageA(t + 2, 0); } } // Au0 dead after q1

      // --- MFMA quadrant ---
      __builtin_amdgcn_s_setprio(1);
#pragma unroll
      for (int mi2 = 0; mi2 < 2; mi2++)
#pragma unroll
        for (int n = 0; n < 4; n++)
#pragma unroll
          for (int kk = 0; kk < 2; kk++)
            acc[q * 2 + mi2][n] = __builtin_amdgcn_mfma_f32_16x16x32_bf16(
                af[mi2][kk], bfr[n][kk], acc[q * 2 + mi2][n], 0, 0, 0);
      __builtin_amdgcn_s_setprio(0);

      // --- barriers: q1-end, q3-end (tile pacing + counted vmcnt) ---
      if (q == 1) {
        __builtin_amdgcn_s_barrier();
      } else if (q == 3) {
        if (t < NT - 2)       { WAITV(6); }
        else if (t == NT - 2) { WAITV(0); }
        __builtin_amdgcn_s_barrier();
      }
    }
  }

#pragma unroll
  for (int mi = 0; mi < 8; mi++) {
#pragma unroll
    for (int n = 0; n < 4; n++) {
      const int col = bn * 256 + wc * 64 + n * 16 + c;
      const float bv = bias[col];
#pragma unroll
      for (int j = 0; j < 4; j++) {
        const int row = bm * 256 + wr * 128 + mi * 16 + g * 4 + j;
        const float v = (acc[mi][n][j] + bv) * scale;
        const int b = row >> 11, s = row & 2047;
        const int h = col >> 7, d2 = col & 127;
        size_t idx;
        if (mode == 1) idx = (((size_t)(b * HEADS + h)) * SEQ + s) * HD + d2;
        else           idx = (((size_t)(b * HEADS + h)) * HD + d2) * SEQ + s;
        ((bf16*)out)[idx] = (bf16)v;
      }
    }
  }
}

// ---------------- split-K 256x256 GEMM for the output projection ----------------
// grid 16bm x 8bn x 2ks = 256 blocks (1/CU). Each computes the kslice partial
// (NT=16 tiles) with the same 2-barrier schedule; writes bf16 partial [M][N].
__global__ __launch_bounds__(512, 2) void gemm256k_kernel(
    const bf16* __restrict__ A, const bf16* __restrict__ W,
    bf16* __restrict__ P0, bf16* __restrict__ P1)
{
  __shared__ char As_[2 * 32768];
  __shared__ char Bs_[2 * 32768];

  const int nwg = gridDim.x;                 // 256
  const int qch = nwg >> 3;
  const int wg = (blockIdx.x & 7) * qch + (blockIdx.x >> 3);
  const int bm = wg % 16;
  const int rest = wg / 16;
  const int bn = rest & 7;
  const int ks = rest >> 3;                  // 0/1
  bf16* __restrict__ out = ks ? P1 : P0;
  const int kbase = ks * 1024;

  const int tid = threadIdx.x;
  const int lane = tid & 63;
  const int w = tid >> 6;
  const int wr = w >> 2;
  const int wc = w & 3;
  const int g = lane >> 4, c = lane & 15;

  const int srow = tid >> 3;
  const int sslot = tid & 7;
  const int scol = (sslot ^ (srow & 7)) * 8;
  const bf16* Abase = A + (size_t)(bm * 256) * 2048;
  const bf16* Bbase = W + (size_t)(bn * 256) * 2048;

  auto stageB = [&](int T, int u) {
    char* dst = Bs_ + (T & 1) * 32768 + u * 16384;
    const int k0 = kbase + T * 64;
#pragma unroll
    for (int j = 0; j < 2; j++) {
      const int r = u * 128 + srow + j * 64;
      gload_lds16(Bbase + (size_t)r * 2048 + k0 + scol,
                  dst + (size_t)(srow + j * 64) * 128 + sslot * 16);
    }
  };
  auto stageA = [&](int T, int u) {
    char* dst = As_ + (T & 1) * 32768 + u * 16384;
    const int k0 = kbase + T * 64;
#pragma unroll
    for (int j = 0; j < 2; j++) {
      const int r = j * 128 + u * 64 + srow;
      gload_lds16(Abase + (size_t)r * 2048 + k0 + scol,
                  dst + (size_t)(srow + j * 64) * 128 + sslot * 16);
    }
  };

  f32x4 acc[8][4] = {};
  bf16x8 bfr[4][2];

  stageB(0, 0); stageB(0, 1); stageA(0, 0); stageA(0, 1);
  stageB(1, 0); stageB(1, 1); stageA(1, 0);
  WAITV(6);
  __builtin_amdgcn_s_barrier();

  const int NT = 16;
  for (int t = 0; t < NT; t++) {
    const int d = t & 1;
    const char* Aq = As_ + d * 32768;
    const char* Bq = Bs_ + d * 32768;
#pragma unroll
    for (int q = 0; q < 4; q++) {
      bf16x8 af[2][2];
      if (q == 0) {
#pragma unroll
        for (int n = 0; n < 4; n++)
#pragma unroll
          for (int kk = 0; kk < 2; kk++) {
            const int row = wc * 64 + n * 16 + c;
            bfr[n][kk] = *(const bf16x8*)(Bq + (size_t)row * 128 +
                                          (((kk * 4 + g) ^ (c & 7)) * 16));
          }
      }
#pragma unroll
      for (int mi2 = 0; mi2 < 2; mi2++)
#pragma unroll
        for (int kk = 0; kk < 2; kk++) {
          const int row = wr * 128 + (q * 2 + mi2) * 16 + c;
          const int slab = (row >> 6) & 1;
          const int aoff = (row & 63) + ((row >> 7) << 6);
          af[mi2][kk] = *(const bf16x8*)(Aq + slab * 16384 + (size_t)aoff * 128 +
                                         (((kk * 4 + g) ^ (c & 7)) * 16));
        }

      if (q == 0)      { if (t + 1 < NT) stageA(t + 1, 1); }
      else if (q == 2) { if (t + 2 < NT) stageB(t + 2, 0); }
      else if (q == 3) { if (t + 2 < NT) { stageB(t + 2, 1); stageA(t + 2, 0); } }

      __builtin_amdgcn_s_setprio(1);
#pragma unroll
      for (int mi2 = 0; mi2 < 2; mi2++)
#pragma unroll
        for (int n = 0; n < 4; n++)
#pragma unroll
          for (int kk = 0; kk < 2; kk++)
            acc[q * 2 + mi2][n] = __builtin_amdgcn_mfma_f32_16x16x32_bf16(
                af[mi2][kk], bfr[n][kk], acc[q * 2 + mi2][n], 0, 0, 0);
      __builtin_amdgcn_s_setprio(0);

      if (q == 1) {
        __builtin_amdgcn_s_barrier();
      } else if (q == 3) {
        if (t < NT - 2)       { WAITV(6); }
        else if (t == NT - 2) { WAITV(0); }
        __builtin_amdgcn_s_barrier();
      }
    }
  }

#pragma unroll
  for (int mi = 0; mi < 8; mi++) {
#pragma unroll
    for (int n = 0; n < 4; n++) {
      const int col = bn * 256 + wc * 64 + n * 16 + c;
#pragma unroll
      for (int j = 0; j < 4; j++) {
        const int row = bm * 256 + wr * 128 + mi * 16 + g * 4 + j;
        out[(size_t)row * E_DIM + col] = (bf16)acc[mi][n][j];
      }
    }
  }
}

// ---------------- reduce: d_out = P0 + P1 + bias (f32 out) ----------------
__global__ __launch_bounds__(256) void reduce_bias_kernel(
    const bf16* __restrict__ P0, const bf16* __restrict__ P1,
    const float* __restrict__ bias, float* __restrict__ out, int n8)
{
  for (int i = blockIdx.x * 256 + threadIdx.x; i < n8; i += gridDim.x * 256) {
    const bf16x8 a = *(const bf16x8*)(P0 + (size_t)i * 8);
    const bf16x8 b = *(const bf16x8*)(P1 + (size_t)i * 8);
    const int col = (i * 8) & 2047;
    const f32x4 b0 = *(const f32x4*)(bias + col);
    const f32x4 b1 = *(const f32x4*)(bias + col + 4);
    f32x4 o0, o1;
#pragma unroll
    for (int j = 0; j < 4; j++) {
      o0[j] = (float)a[j] + (float)b[j] + b0[j];
      o1[j] = (float)a[4 + j] + (float)b[4 + j] + b1[j];
    }
    *(f32x4*)(out + (size_t)i * 8) = o0;
    *(f32x4*)(out + (size_t)i * 8 + 4) = o1;
  }
}

// ---------------- slots projections ----------------
__global__ __launch_bounds__(256) void slots_proj_kernel(
    const float* __restrict__ slots,
    const float* __restrict__ Wk, const float* __restrict__ bk,
    const float* __restrict__ Wv, const float* __restrict__ bv,
    float* __restrict__ tk, float* __restrict__ tv)
{
  const int col = blockIdx.x * 256 + threadIdx.x;
  const int slot = blockIdx.y;
  const int mat = blockIdx.z;
  const float* W = mat ? Wv : Wk;
  const float* bias = mat ? bv : bk;
  float* out = mat ? tv : tk;
  const float* xr = slots + (size_t)slot * E_DIM;
  const float* wr = W + (size_t)col * E_DIM;
  float acc = 0.f;
  for (int k = 0; k < E_DIM; k += 4) {
    const f32x4 a = *(const f32x4*)(xr + k);
    const f32x4 b4 = *(const f32x4*)(wr + k);
#pragma unroll
    for (int i = 0; i < 4; i++) acc += a[i] * b4[i];
  }
  out[(size_t)slot * E_DIM + col] = acc + bias[col];
}

// ---------------- flash attention: 8-wave 32x32, T15 deferred-PV (round-11) ------------
__global__ __launch_bounds__(512) void flash_attn_kernel(
    const bf16* __restrict__ Qg, const bf16* __restrict__ Kg,
    const bf16* __restrict__ Vtg, bf16* __restrict__ Og)
{
  __shared__ char Ks[3][64 * 256];
  __shared__ char Vs[3][128 * 128];

  const int orig = blockIdx.x;
  const int logical = (orig & 7) * 32 + (orig >> 3);
  const int qt = logical & 7;
  const int bh = logical >> 3;

  const int tid = threadIdx.x;
  const int lane = tid & 63;
  const int w = tid >> 6;
  const int q = lane & 31;
  const int hi = lane >> 5;
  const int b = bh >> 4, h = bh & 15;
  const int q0 = qt * 256 + w * 32;

  const bf16* Qb = Qg + ((size_t)bh * SEQ + q0) * HD;
  const bf16* Kb = Kg + (size_t)bh * SEQ * HD;
  const bf16* Vb = Vtg + (size_t)bh * HD * SEQ;

  auto stage = [&](int kv0, int buf) {
#pragma unroll
    for (int i = 0; i < 2; i++) {
      const int p = (tid + i * 512) * 16;
      { const int r = p >> 8; const int s16 = (p >> 4) & 15;
        gload_lds16(Kb + (size_t)(kv0 + r) * HD + (s16 ^ (r & 15)) * 8, &Ks[0][0] + buf * 16384 + p); }
      { const int r = p >> 7; const int s8 = (p >> 4) & 7;
        gload_lds16(Vb + (size_t)r * SEQ + kv0 + (s8 ^ (r & 7)) * 8, &Vs[0][0] + buf * 16384 + p); }
    }
  };

  bf16x8 qf[8];
#pragma unroll
  for (int kc = 0; kc < 8; kc++)
    qf[kc] = *(const bf16x8*)(Qb + (size_t)q * HD + kc * 16 + hi * 8);

  f32x16 o[4] = {};
  float mrun = -1e30f, lsum = 0.f;
  bf16x8 pbo[2][2];

  stage(0, 0);
  __syncthreads();

  int prv = 2, cur = 0, nxt = 1;
  const int NT = SEQ / 64;

  for (int t = 0; t < NT; t++) {
    if (t + 1 < NT) stage((t + 1) * 64, nxt);

    f32x16 st[2] = {};
    const char* Kc = &Ks[0][0] + cur * 16384;
    __builtin_amdgcn_s_setprio(1);
#pragma unroll
    for (int kc = 0; kc < 8; kc++) {
#pragma unroll
      for (int blk = 0; blk < 2; blk++) {
        const int rt = blk * 32 + q;
        const int sl = (2 * kc + hi) ^ (rt & 15);
        const bf16x8 kf = *(const bf16x8*)(Kc + rt * 256 + sl * 16);
        st[blk] = __builtin_amdgcn_mfma_f32_32x32x16_bf16(kf, qf[kc], st[blk], 0, 0, 0);
      }
    }
    __builtin_amdgcn_s_setprio(0);

    float tm[16];
#pragma unroll
    for (int i = 0; i < 16; i++) tm[i] = fmaxf(st[0][i], st[1][i]);
#pragma unroll
    for (int s2 = 8; s2 > 0; s2 >>= 1)
#pragma unroll
      for (int i = 0; i < 8; i++) if (i < s2) tm[i] = fmaxf(tm[i], tm[i + s2]);
    float lm = tm[0];
    lm = fmaxf(lm, __shfl_xor(lm, 32));
    float fsc = 1.0f;
    const bool resc = __any(lm > mrun + 8.0f);
    if (resc) {
      const float mn = fmaxf(mrun, lm);
      fsc = exp2f(mrun - mn);
      mrun = mn;
    }

    float ps0 = 0.f, ps1 = 0.f, ps2 = 0.f, ps3 = 0.f;
#pragma unroll
    for (int blk = 0; blk < 2; blk++)
#pragma unroll
      for (int i = 0; i < 16; i += 4) {
        const float p0 = exp2f(st[blk][i]     - mrun);
        const float p1 = exp2f(st[blk][i + 1] - mrun);
        const float p2 = exp2f(st[blk][i + 2] - mrun);
        const float p3 = exp2f(st[blk][i + 3] - mrun);
        st[blk][i] = p0; st[blk][i + 1] = p1; st[blk][i + 2] = p2; st[blk][i + 3] = p3;
        ps0 += p0; ps1 += p1; ps2 += p2; ps3 += p3;
      }
    lsum = lsum * fsc + ((ps0 + ps1) + (ps2 + ps3));

    bf16x8 pbn[2][2];
#pragma unroll
    for (int blk = 0; blk < 2; blk++)
#pragma unroll
      for (int c2 = 0; c2 < 2; c2++) {
        bf16x4 Lv, Hv;
#pragma unroll
        for (int i = 0; i < 4; i++) {
          Lv[i] = (bf16)st[blk][8 * c2 + i];
          Hv[i] = (bf16)st[blk][8 * c2 + 4 + i];
        }
        const u32x2 Lu = __builtin_bit_cast(u32x2, Lv);
        const u32x2 Hu = __builtin_bit_cast(u32x2, Hv);
        const uint32_t s0 = hi ? Lu.x : Hu.x;
        const uint32_t s1 = hi ? Lu.y : Hu.y;
        const uint32_t x0 = (uint32_t)__shfl_xor((int)s0, 32);
        const uint32_t x1 = (uint32_t)__shfl_xor((int)s1, 32);
        u32x4 bv;
        bv.x = hi ? x0 : Lu.x;
        bv.y = hi ? x1 : Lu.y;
        bv.z = hi ? Hu.x : x0;
        bv.w = hi ? Hu.y : x1;
        pbn[blk][c2] = __builtin_bit_cast(bf16x8, bv);
      }

    if (t > 0) {
      const char* Vc = &Vs[0][0] + prv * 16384;
#pragma unroll
      for (int db = 0; db < 4; db++) {
        const int rt = db * 32 + q;
#pragma unroll
        for (int blk = 0; blk < 2; blk++)
#pragma unroll
          for (int c2 = 0; c2 < 2; c2++) {
            const int sl = (blk * 4 + c2 * 2 + hi) ^ (rt & 7);
            const bf16x8 vf = *(const bf16x8*)(Vc + rt * 128 + sl * 16);
            o[db] = __builtin_amdgcn_mfma_f32_32x32x16_bf16(vf, pbo[blk][c2], o[db], 0, 0, 0);
          }
      }
    }

    if (resc) {
#pragma unroll
      for (int db = 0; db < 4; db++)
#pragma unroll
        for (int i = 0; i < 16; i++) o[db][i] *= fsc;
    }

#pragma unroll
    for (int blk = 0; blk < 2; blk++)
#pragma unroll
      for (int c2 = 0; c2 < 2; c2++) pbo[blk][c2] = pbn[blk][c2];

    __syncthreads();
    const int tmp = prv; prv = cur; cur = nxt; nxt = tmp;
  }

  {
    const char* Vc = &Vs[0][0] + prv * 16384;
#pragma unroll
    for (int db = 0; db < 4; db++) {
      const int rt = db * 32 + q;
#pragma unroll
      for (int blk = 0; blk < 2; blk++)
#pragma unroll
        for (int c2 = 0; c2 < 2; c2++) {
          const int sl = (blk * 4 + c2 * 2 + hi) ^ (rt & 7);
          const bf16x8 vf = *(const bf16x8*)(Vc + rt * 128 + sl * 16);
          o[db] = __builtin_amdgcn_mfma_f32_32x32x16_bf16(vf, pbo[blk][c2], o[db], 0, 0, 0);
        }
    }
  }

  const float lt = lsum + __shfl_xor(lsum, 32);
  const float linv = 1.0f / lt;
  bf16* Orow = Og + ((size_t)b * SEQ + q0 + q) * E_DIM + h * HD;
#pragma unroll
  for (int db = 0; db < 4; db++)
#pragma unroll
    for (int g4 = 0; g4 < 4; g4++) {
      bf16x4 ov;
#pragma unroll
      for (int i = 0; i < 4; i++) ov[i] = (bf16)(o[db][g4 * 4 + i] * linv);
      *(bf16x4*)(Orow + db * 32 + g4 * 8 + hi * 4) = ov;
    }
}

// ---------------- fused thought cross-attn + LayerNorm ----------------
__global__ __launch_bounds__(256) void thought_ln_kernel(
    const bf16* __restrict__ TQ, const float* __restrict__ TK,
    const float* __restrict__ TV, const bf16* __restrict__ ATT,
    const float* __restrict__ gamma, const float* __restrict__ beta,
    bf16* __restrict__ Y)
{
  __shared__ float wsum[4], wsq[4];
  const int tid = threadIdx.x;
  const int lane = tid & 63;
  const int w = tid >> 6;
  const int tok = blockIdx.x;
  const int b = tok >> 11, s = tok & 2047;
  const int e0 = tid * 8;
  const int h = e0 >> 7;
  const int d0 = e0 & 127;

  const bf16x8 av = *(const bf16x8*)(ATT + (size_t)tok * E_DIM + e0);
  float v[8];
#pragma unroll
  for (int i = 0; i < 8; i++) v[i] = (float)av[i];

  const bf16x8 qv8 = *(const bf16x8*)(TQ + (((size_t)(b * HEADS + h)) * SEQ + s) * HD + d0);
  float qv[8];
#pragma unroll
  for (int i = 0; i < 8; i++) qv[i] = (float)qv8[i];

  float dts[NSLOT];
#pragma unroll
  for (int sl = 0; sl < NSLOT; sl++) {
    const float* tkr = TK + (size_t)sl * E_DIM + e0;
    const f32x4 k0 = *(const f32x4*)(tkr);
    const f32x4 k1 = *(const f32x4*)(tkr + 4);
    float dp = 0.f;
#pragma unroll
    for (int i = 0; i < 4; i++) dp += qv[i] * k0[i] + qv[4 + i] * k1[i];
    dp += __shfl_xor(dp, 1);
    dp += __shfl_xor(dp, 2);
    dp += __shfl_xor(dp, 4);
    dp += __shfl_xor(dp, 8);
    dts[sl] = dp;
  }
  float mx = dts[0];
#pragma unroll
  for (int sl = 1; sl < NSLOT; sl++) mx = fmaxf(mx, dts[sl]);
  float p[NSLOT], den = 0.f;
#pragma unroll
  for (int sl = 0; sl < NSLOT; sl++) { p[sl] = exp2f(dts[sl] - mx); den += p[sl]; }
  const float dinv = 1.0f / den;
#pragma unroll
  for (int sl = 0; sl < NSLOT; sl++) {
    const float pn = p[sl] * dinv;
    const float* tvr = TV + (size_t)sl * E_DIM + e0;
    const f32x4 v0 = *(const f32x4*)(tvr);
    const f32x4 v1 = *(const f32x4*)(tvr + 4);
#pragma unroll
    for (int i = 0; i < 4; i++) { v[i] += pn * v0[i]; v[4 + i] += pn * v1[i]; }
  }

  float sm = 0.f, sq = 0.f;
#pragma unroll
  for (int i = 0; i < 8; i++) { sm += v[i]; sq += v[i] * v[i]; }
#pragma unroll
  for (int d = 1; d < 64; d <<= 1) { sm += __shfl_xor(sm, d); sq += __shfl_xor(sq, d); }
  if (lane == 0) { wsum[w] = sm; wsq[w] = sq; }
  __syncthreads();
  const float ts = wsum[0] + wsum[1] + wsum[2] + wsum[3];
  const float tq2 = wsq[0] + wsq[1] + wsq[2] + wsq[3];
  const float mean = ts * (1.f / E_DIM);
  const float var = tq2 * (1.f / E_DIM) - mean * mean;
  const float rstd = rsqrtf(var + 1e-5f);
  const f32x4 g0 = *(const f32x4*)(gamma + e0);
  const f32x4 g1 = *(const f32x4*)(gamma + e0 + 4);
  const f32x4 b0 = *(const f32x4*)(beta + e0);
  const f32x4 b1 = *(const f32x4*)(beta + e0 + 4);
  bf16x8 outv;
#pragma unroll
  for (int i = 0; i < 4; i++) {
    outv[i]     = (bf16)((v[i]     - mean) * rstd * g0[i] + b0[i]);
    outv[4 + i] = (bf16)((v[4 + i] - mean) * rstd * g1[i] + b1[i]);
  }
  *(bf16x8*)(Y + (size_t)tok * E_DIM + e0) = outv;
}

extern "C" void kernel_launch(void* const* d_in, const int* in_sizes, int n_in,
                              void* d_out, int out_size, void* d_ws, size_t ws_size,
                              hipStream_t stream) {
  (void)in_sizes; (void)n_in; (void)out_size; (void)ws_size;
  const float* x     = (const float*)d_in[0];
  const float* slots = (const float*)d_in[1];
  const float* Wq  = (const float*)d_in[2];   const float* bq  = (const float*)d_in[3];
  const float* Wk  = (const float*)d_in[4];   const float* bk  = (const float*)d_in[5];
  const float* Wv  = (const float*)d_in[6];   const float* bv  = (const float*)d_in[7];
  const float* Wtq = (const float*)d_in[8];   const float* btq = (const float*)d_in[9];
  const float* Wtk = (const float*)d_in[10];  const float* btk = (const float*)d_in[11];
  const float* Wtv = (const float*)d_in[12];  const float* btv = (const float*)d_in[13];
  const float* Wo  = (const float*)d_in[14];  const float* bo  = (const float*)d_in[15];
  const float* gamma = (const float*)d_in[16];
  const float* beta  = (const float*)d_in[17];

  uint8_t* ws = (uint8_t*)d_ws;
  const size_t BUF  = (size_t)NTOK * E_DIM * sizeof(bf16);    // 16 MiB
  const size_t WBUF = (size_t)E_DIM * E_DIM * sizeof(bf16);   // 8 MiB
  bf16* xb   = (bf16*)(ws + 0 * BUF);
  bf16* qb   = (bf16*)(ws + 1 * BUF);          // [B,H,S,D] (pre-scaled)
  bf16* kb   = (bf16*)(ws + 2 * BUF);          // [B,H,S,D]; dead after flash -> P0
  bf16* vtb  = (bf16*)(ws + 3 * BUF);          // [B,H,D,S]; dead after flash -> P1
  bf16* tqb  = (bf16*)(ws + 4 * BUF);          // [B,H,S,D] (pre-scaled)
  bf16* attb = (bf16*)(ws + 5 * BUF);          // [B,S,E] flash output
  bf16* nrmb = qb;                             // alias: qb dead after flash
  bf16* P0   = kb;                             // split-K partials (reuse dead bufs)
  bf16* P1   = vtb;
  uint8_t* wp = ws + 6 * BUF;
  bf16* Wqb  = (bf16*)(wp + 0 * WBUF);
  bf16* Wkb  = (bf16*)(wp + 1 * WBUF);
  bf16* Wvb  = (bf16*)(wp + 2 * WBUF);
  bf16* Wtqb = (bf16*)(wp + 3 * WBUF);
  bf16* Wob  = (bf16*)(wp + 4 * WBUF);
  float* tkb = (float*)(wp + 5 * WBUF);
  float* tvb = (float*)(wp + 5 * WBUF + 128 * 1024);

  // --- convert f32 -> bf16 (x + batched 5 weights) ---
  const int WN8 = E_DIM * E_DIM / 8;
  const int XN8 = NTOK * E_DIM / 8;
  cvt_f32_bf16_kernel<<<dim3(2048), 256, 0, stream>>>(x, xb, XN8);
  CvtArgs ca;
  ca.src[0] = Wq;  ca.dst[0] = Wqb;
  ca.src[1] = Wk;  ca.dst[1] = Wkb;
  ca.src[2] = Wv;  ca.dst[2] = Wvb;
  ca.src[3] = Wtq; ca.dst[3] = Wtqb;
  ca.src[4] = Wo;  ca.dst[4] = Wob;
  cvt5_kernel<<<dim3(1024, 5), 256, 0, stream>>>(ca, WN8);

  // --- projections (Q and TQ pre-scaled by 1/sqrt(D)*log2e) ---
  ProjArgs pa;
  pa.W[0] = Wqb;  pa.bias[0] = bq;  pa.out[0] = qb;  pa.mode[0] = 1; pa.scale[0] = QSCALE;
  pa.W[1] = Wkb;  pa.bias[1] = bk;  pa.out[1] = kb;  pa.mode[1] = 1; pa.scale[1] = 1.0f;
  pa.W[2] = Wvb;  pa.bias[2] = bv;  pa.out[2] = vtb; pa.mode[2] = 2; pa.scale[2] = 1.0f;
  pa.W[3] = Wtqb; pa.bias[3] = btq; pa.out[3] = tqb; pa.mode[3] = 1; pa.scale[3] = QSCALE;
  gemm256_kernel<<<dim3(16 * 8 * 4), 512, 0, stream>>>(xb, pa, 16, 8);

  slots_proj_kernel<<<dim3(E_DIM / 256, NSLOT, 2), 256, 0, stream>>>(
      slots, Wtk, btk, Wtv, btv, tkb, tvb);

  // --- attention streams ---
  flash_attn_kernel<<<dim3((SEQ / 256) * BATCH * HEADS), 512, 0, stream>>>(
      qb, kb, vtb, attb);
  thought_ln_kernel<<<dim3(NTOK), 256, 0, stream>>>(
      tqb, tkb, tvb, attb, gamma, beta, nrmb);

  // --- output projection: split-K x2 (256 blocks = 1/CU) + reduce ---
  gemm256k_kernel<<<dim3(256), 512, 0, stream>>>(nrmb, Wob, P0, P1);
  reduce_bias_kernel<<<dim3(2048), 256, 0, stream>>>(
      P0, P1, bo, (float*)d_out, NTOK * E_DIM / 8);
}